// Round 1
// baseline (795.815 us; speedup 1.0000x reference)
//
#include <hip/hip_runtime.h>
#include <math.h>

static constexpr int TPB = 256;

// ---------------- degree / normalization ----------------

__global__ void k_deg_init(float* deg, int n) {
    int i = blockIdx.x * TPB + threadIdx.x;
    if (i < n) deg[i] = 1.0f;  // self-loop contributes 1
}

__global__ void k_deg_count(const int* __restrict__ dst, float* deg, int E) {
    int e = blockIdx.x * TPB + threadIdx.x;
    if (e < E) atomicAdd(&deg[dst[e]], 1.0f);
}

__global__ void k_dinv(float* deg, int n) {
    int i = blockIdx.x * TPB + threadIdx.x;
    if (i < n) deg[i] = rsqrtf(deg[i]);  // in-place: deg buffer becomes dinv
}

// ---------------- layer 1 GEMM: H1 = x @ W1 ; agg = H1 * dinv^2 (self loop) ----------------

__global__ __launch_bounds__(256) void k_gemm1(const float* __restrict__ x,
                                               const float* __restrict__ W,
                                               const float* __restrict__ dinv,
                                               float* __restrict__ H,
                                               float* __restrict__ agg, int n) {
    __shared__ float Wl[128 * 128];  // 64 KiB
    for (int i = threadIdx.x; i < 128 * 128; i += TPB) Wl[i] = W[i];
    __syncthreads();

    const int ROWS = 32;
    int row0 = blockIdx.x * ROWS;
    int col = threadIdx.x & 127;
    int rs = threadIdx.x >> 7;  // 0 or 1: two rows in flight per block
    int rend = min(row0 + ROWS, n);
    for (int r = row0 + rs; r < rend; r += 2) {
        const float* xr = x + (size_t)r * 128;
        float acc = 0.f;
#pragma unroll
        for (int k = 0; k < 128; ++k) acc = fmaf(xr[k], Wl[k * 128 + col], acc);
        size_t idx = (size_t)r * 128 + col;
        H[idx] = acc;
        float di = dinv[r];
        agg[idx] = acc * di * di;  // self-loop message, seeds the aggregation buffer
    }
}

// ---------------- layer 1 edge scatter: agg[dst] += H1[src] * dinv[src]*dinv[dst] ----------------

__global__ void k_scatter1(const float* __restrict__ H, const float* __restrict__ dinv,
                           const int* __restrict__ src, const int* __restrict__ dst,
                           float* agg, int E) {
    size_t gid = (size_t)blockIdx.x * TPB + threadIdx.x;
    int e = (int)(gid >> 7);
    if (e >= E) return;
    int f = (int)(gid & 127);
    int s = src[e], d = dst[e];
    float coef = dinv[s] * dinv[d];
    atomicAdd(&agg[(size_t)d * 128 + f], H[(size_t)s * 128 + f] * coef);
}

// ---------------- bias + relu ----------------

__global__ void k_bias_relu(const float* __restrict__ agg, const float* __restrict__ b,
                            float* __restrict__ h, size_t total) {
    size_t i = (size_t)blockIdx.x * TPB + threadIdx.x;
    if (i < total) h[i] = fmaxf(agg[i] + b[i & 127], 0.f);
}

// ---------------- layer 2 GEMM: H2 = h @ W2 ; out = H2 * dinv^2 ----------------

__global__ __launch_bounds__(256) void k_gemm2(const float* __restrict__ h,
                                               const float* __restrict__ W,
                                               const float* __restrict__ dinv,
                                               float* __restrict__ H2,
                                               float* __restrict__ out, int n) {
    __shared__ float Wl[128 * 40];  // 20 KiB
    for (int i = threadIdx.x; i < 128 * 40; i += TPB) Wl[i] = W[i];
    __syncthreads();

    size_t total = (size_t)n * 40;
    for (size_t idx = (size_t)blockIdx.x * TPB + threadIdx.x; idx < total;
         idx += (size_t)gridDim.x * TPB) {
        int row = (int)(idx / 40);
        int c = (int)(idx % 40);
        const float* hr = h + (size_t)row * 128;
        float acc = 0.f;
#pragma unroll
        for (int k = 0; k < 128; ++k) acc = fmaf(hr[k], Wl[k * 40 + c], acc);
        H2[idx] = acc;
        float di = dinv[row];
        out[idx] = acc * di * di;  // self-loop message
    }
}

// ---------------- layer 2 edge scatter ----------------

__global__ void k_scatter2(const float* __restrict__ H2, const float* __restrict__ dinv,
                           const int* __restrict__ src, const int* __restrict__ dst,
                           float* out, int E) {
    size_t gid = (size_t)blockIdx.x * TPB + threadIdx.x;
    if (gid >= (size_t)E * 40) return;
    int e = (int)(gid / 40);
    int c = (int)(gid % 40);
    int s = src[e], d = dst[e];
    float coef = dinv[s] * dinv[d];
    atomicAdd(&out[(size_t)d * 40 + c], H2[(size_t)s * 40 + c] * coef);
}

// ---------------- bias + log_softmax over 40 classes, one wave per row ----------------

__global__ void k_lsm(float* __restrict__ out, const float* __restrict__ b, int n) {
    int wid = threadIdx.x >> 6;
    int lane = threadIdx.x & 63;
    int row = blockIdx.x * 4 + wid;
    if (row >= n) return;
    float* r = out + (size_t)row * 40;

    float val = 0.f;
    float m = -INFINITY;
    if (lane < 40) {
        val = r[lane] + b[lane];
        m = val;
    }
#pragma unroll
    for (int off = 32; off; off >>= 1) m = fmaxf(m, __shfl_xor(m, off));
    float e = (lane < 40) ? expf(val - m) : 0.f;
    float s = e;
#pragma unroll
    for (int off = 32; off; off >>= 1) s += __shfl_xor(s, off);
    float ls = logf(s);
    if (lane < 40) r[lane] = val - m - ls;
}

// ---------------- launch ----------------

extern "C" void kernel_launch(void* const* d_in, const int* in_sizes, int n_in,
                              void* d_out, int out_size, void* d_ws, size_t ws_size,
                              hipStream_t stream) {
    const float* x  = (const float*)d_in[0];
    const int*   ei = (const int*)d_in[1];
    const float* W1 = (const float*)d_in[2];
    const float* b1 = (const float*)d_in[3];
    const float* W2 = (const float*)d_in[4];
    const float* b2 = (const float*)d_in[5];

    int n = in_sizes[0] / 128;
    int E = in_sizes[1] / 2;
    const int* src = ei;        // edge_index[0]
    const int* dst = ei + E;    // edge_index[1]

    float* out  = (float*)d_out;
    float* ws   = (float*)d_ws;
    float* dinv = ws;                          // n floats (deg, then rsqrt in place)
    float* bufA = ws + n;                      // n*128 (H1, then relu(h1))
    float* bufB = bufA + (size_t)n * 128;      // n*128 (agg1, then H2 [n*40])

    int nb_n = (n + TPB - 1) / TPB;
    k_deg_init<<<nb_n, TPB, 0, stream>>>(dinv, n);
    k_deg_count<<<(E + TPB - 1) / TPB, TPB, 0, stream>>>(dst, dinv, E);
    k_dinv<<<nb_n, TPB, 0, stream>>>(dinv, n);

    k_gemm1<<<(n + 31) / 32, TPB, 0, stream>>>(x, W1, dinv, bufA, bufB, n);

    size_t sc1_threads = (size_t)E * 128;
    k_scatter1<<<(int)((sc1_threads + TPB - 1) / TPB), TPB, 0, stream>>>(bufA, dinv, src, dst,
                                                                          bufB, E);

    size_t tot1 = (size_t)n * 128;
    k_bias_relu<<<(int)((tot1 + TPB - 1) / TPB), TPB, 0, stream>>>(bufB, b1, bufA, tot1);

    size_t tot2 = (size_t)n * 40;
    k_gemm2<<<(int)((tot2 + TPB - 1) / TPB), TPB, 0, stream>>>(bufA, W2, dinv, bufB, out, n);

    size_t sc2_threads = (size_t)E * 40;
    k_scatter2<<<(int)((sc2_threads + TPB - 1) / TPB), TPB, 0, stream>>>(bufB, dinv, src, dst,
                                                                          out, E);

    k_lsm<<<(n + 3) / 4, TPB, 0, stream>>>(out, b2, n);
}

// Round 2
// 297.868 us; speedup vs baseline: 2.6717x; 2.6717x over previous
//
#include <hip/hip_runtime.h>
#include <math.h>

static constexpr int TPB = 256;

// ---------------- CSR build ----------------

__global__ void k_zero(int* p, int n) {
    int i = blockIdx.x * TPB + threadIdx.x;
    if (i < n) p[i] = 0;
}

__global__ void k_hist(const int* __restrict__ dst, int* __restrict__ cnt, int E) {
    int e = blockIdx.x * TPB + threadIdx.x;
    if (e < E) atomicAdd(&cnt[dst[e]], 1);
}

// per-block inclusive scan of cnt -> rp[i+1]; block totals -> bsum
__global__ void k_scan_block(const int* __restrict__ cnt, int* __restrict__ rp,
                             int* __restrict__ bsum, int n) {
    __shared__ int s[TPB];
    int t = threadIdx.x;
    int i = blockIdx.x * TPB + t;
    int v = (i < n) ? cnt[i] : 0;
    s[t] = v;
    __syncthreads();
    for (int off = 1; off < TPB; off <<= 1) {
        int a = (t >= off) ? s[t - off] : 0;
        __syncthreads();
        s[t] += a;
        __syncthreads();
    }
    if (i < n) rp[i + 1] = s[t];
    if (t == TPB - 1) bsum[blockIdx.x] = s[t];
}

// exclusive scan of block sums (nb <= 256)
__global__ void k_scan_top(int* bsum, int nb) {
    __shared__ int s[TPB];
    int t = threadIdx.x;
    int v = (t < nb) ? bsum[t] : 0;
    s[t] = v;
    __syncthreads();
    for (int off = 1; off < TPB; off <<= 1) {
        int a = (t >= off) ? s[t - off] : 0;
        __syncthreads();
        s[t] += a;
        __syncthreads();
    }
    if (t < nb) bsum[t] = s[t] - v;  // exclusive
}

__global__ void k_scan_add(int* rp, const int* __restrict__ bsum, int n) {
    int i = blockIdx.x * TPB + threadIdx.x;
    if (i < n) rp[i + 1] += bsum[i >> 8];
    if (i == 0) rp[0] = 0;
}

// nxt[i] = rp[i] (allocation cursor), dinv[i] = rsqrt(1+deg)
__global__ void k_prep(const int* __restrict__ cnt, const int* __restrict__ rp,
                       int* __restrict__ nxt, float* __restrict__ dinv, int n) {
    int i = blockIdx.x * TPB + threadIdx.x;
    if (i < n) {
        nxt[i] = rp[i];
        dinv[i] = rsqrtf(1.0f + (float)cnt[i]);
    }
}

__global__ void k_fill(const int* __restrict__ src, const int* __restrict__ dst, int* nxt,
                       int* __restrict__ csrc, int E) {
    int e = blockIdx.x * TPB + threadIdx.x;
    if (e < E) {
        int d = dst[e];
        int pos = atomicAdd(&nxt[d], 1);
        csrc[pos] = src[e];
    }
}

// ---------------- GEMM1: H = x @ W1  (128x128), 4x4 micro-tile per thread ----------------

#define COMP(v, j) ((j) == 0 ? (v).x : ((j) == 1 ? (v).y : ((j) == 2 ? (v).z : (v).w)))

__global__ __launch_bounds__(256) void k_gemm1(const float* __restrict__ x,
                                               const float* __restrict__ W,
                                               float* __restrict__ H, int n) {
    __shared__ float Wl[128 * 128];  // 64 KiB
    {
        const float4* W4 = (const float4*)W;
        float4* L4 = (float4*)Wl;
        for (int i = threadIdx.x; i < 128 * 32; i += TPB) L4[i] = W4[i];
    }
    __syncthreads();
    int t = threadIdx.x;
    int cg = t & 31;                         // col group: cols cg*4 .. cg*4+3
    int r0 = blockIdx.x * 32 + (t >> 5) * 4; // 4 rows per thread, 32 rows per block
    if (r0 >= n) return;
    int r1 = min(r0 + 1, n - 1), r2 = min(r0 + 2, n - 1), r3 = min(r0 + 3, n - 1);
    const float* x0 = x + (size_t)r0 * 128;
    const float* x1 = x + (size_t)r1 * 128;
    const float* x2 = x + (size_t)r2 * 128;
    const float* x3 = x + (size_t)r3 * 128;
    float4 a0 = make_float4(0, 0, 0, 0), a1 = a0, a2 = a0, a3 = a0;
    const float4* L4 = (const float4*)Wl;
    for (int k = 0; k < 128; k += 4) {
        float4 xa = *(const float4*)(x0 + k);
        float4 xb = *(const float4*)(x1 + k);
        float4 xc = *(const float4*)(x2 + k);
        float4 xd = *(const float4*)(x3 + k);
#pragma unroll
        for (int j = 0; j < 4; ++j) {
            float4 w = L4[(k + j) * 32 + cg];
            float va = COMP(xa, j), vb = COMP(xb, j), vc = COMP(xc, j), vd = COMP(xd, j);
            a0.x = fmaf(va, w.x, a0.x); a0.y = fmaf(va, w.y, a0.y);
            a0.z = fmaf(va, w.z, a0.z); a0.w = fmaf(va, w.w, a0.w);
            a1.x = fmaf(vb, w.x, a1.x); a1.y = fmaf(vb, w.y, a1.y);
            a1.z = fmaf(vb, w.z, a1.z); a1.w = fmaf(vb, w.w, a1.w);
            a2.x = fmaf(vc, w.x, a2.x); a2.y = fmaf(vc, w.y, a2.y);
            a2.z = fmaf(vc, w.z, a2.z); a2.w = fmaf(vc, w.w, a2.w);
            a3.x = fmaf(vd, w.x, a3.x); a3.y = fmaf(vd, w.y, a3.y);
            a3.z = fmaf(vd, w.z, a3.z); a3.w = fmaf(vd, w.w, a3.w);
        }
    }
    *(float4*)(H + (size_t)r0 * 128 + cg * 4) = a0;
    if (r0 + 1 < n) *(float4*)(H + (size_t)(r0 + 1) * 128 + cg * 4) = a1;
    if (r0 + 2 < n) *(float4*)(H + (size_t)(r0 + 2) * 128 + cg * 4) = a2;
    if (r0 + 3 < n) *(float4*)(H + (size_t)(r0 + 3) * 128 + cg * 4) = a3;
}

// ---------------- agg1: h = relu( sum_in H[s]*dinv[s]*dinv[i] + H[i]*dinv[i]^2 + b1 ) ----------------

__global__ __launch_bounds__(256) void k_agg1(const float* __restrict__ H,
                                              const float* __restrict__ dinv,
                                              const int* __restrict__ rp,
                                              const int* __restrict__ csrc,
                                              const float* __restrict__ b1,
                                              float* __restrict__ hout, int n) {
    int i = blockIdx.x * 4 + (threadIdx.x >> 6);
    if (i >= n) return;
    int lane = threadIdx.x & 63;
    float di = dinv[i];
    const float2* Hv = (const float2*)H;
    float2 acc = Hv[(size_t)i * 64 + lane];
    float s2 = di * di;
    acc.x *= s2;
    acc.y *= s2;
    int e = rp[i], end = rp[i + 1];
    for (; e + 1 < end; e += 2) {
        int sA = csrc[e], sB = csrc[e + 1];
        float cA = dinv[sA] * di, cB = dinv[sB] * di;
        float2 va = Hv[(size_t)sA * 64 + lane];
        float2 vb = Hv[(size_t)sB * 64 + lane];
        acc.x = fmaf(va.x, cA, acc.x); acc.y = fmaf(va.y, cA, acc.y);
        acc.x = fmaf(vb.x, cB, acc.x); acc.y = fmaf(vb.y, cB, acc.y);
    }
    if (e < end) {
        int sA = csrc[e];
        float cA = dinv[sA] * di;
        float2 va = Hv[(size_t)sA * 64 + lane];
        acc.x = fmaf(va.x, cA, acc.x); acc.y = fmaf(va.y, cA, acc.y);
    }
    float2 bb = ((const float2*)b1)[lane];
    acc.x = fmaxf(acc.x + bb.x, 0.f);
    acc.y = fmaxf(acc.y + bb.y, 0.f);
    ((float2*)hout)[(size_t)i * 64 + lane] = acc;
}

// ---------------- GEMM2: H2 = h @ W2 (128x40), 4 rows x 4 cols per thread ----------------

__global__ __launch_bounds__(256) void k_gemm2(const float* __restrict__ h,
                                               const float* __restrict__ W,
                                               float* __restrict__ H2, int n) {
    __shared__ float Wl[128 * 40];  // 20 KiB
    {
        const float4* W4 = (const float4*)W;
        float4* L4 = (float4*)Wl;
        for (int i = threadIdx.x; i < 128 * 10; i += TPB) L4[i] = W4[i];
    }
    __syncthreads();
    int t = threadIdx.x;
    if (t >= 250) return;
    int cg = t % 10;  // col group: cols cg*4 .. cg*4+3
    int rb = t / 10;
    int r0 = blockIdx.x * 100 + rb * 4;
    if (r0 >= n) return;
    int r1 = min(r0 + 1, n - 1), r2 = min(r0 + 2, n - 1), r3 = min(r0 + 3, n - 1);
    const float* h0 = h + (size_t)r0 * 128;
    const float* h1 = h + (size_t)r1 * 128;
    const float* h2 = h + (size_t)r2 * 128;
    const float* h3 = h + (size_t)r3 * 128;
    float4 a0 = make_float4(0, 0, 0, 0), a1 = a0, a2 = a0, a3 = a0;
    const float4* L4 = (const float4*)Wl;
    for (int k = 0; k < 128; k += 4) {
        float4 xa = *(const float4*)(h0 + k);
        float4 xb = *(const float4*)(h1 + k);
        float4 xc = *(const float4*)(h2 + k);
        float4 xd = *(const float4*)(h3 + k);
#pragma unroll
        for (int j = 0; j < 4; ++j) {
            float4 w = L4[(k + j) * 10 + cg];
            float va = COMP(xa, j), vb = COMP(xb, j), vc = COMP(xc, j), vd = COMP(xd, j);
            a0.x = fmaf(va, w.x, a0.x); a0.y = fmaf(va, w.y, a0.y);
            a0.z = fmaf(va, w.z, a0.z); a0.w = fmaf(va, w.w, a0.w);
            a1.x = fmaf(vb, w.x, a1.x); a1.y = fmaf(vb, w.y, a1.y);
            a1.z = fmaf(vb, w.z, a1.z); a1.w = fmaf(vb, w.w, a1.w);
            a2.x = fmaf(vc, w.x, a2.x); a2.y = fmaf(vc, w.y, a2.y);
            a2.z = fmaf(vc, w.z, a2.z); a2.w = fmaf(vc, w.w, a2.w);
            a3.x = fmaf(vd, w.x, a3.x); a3.y = fmaf(vd, w.y, a3.y);
            a3.z = fmaf(vd, w.z, a3.z); a3.w = fmaf(vd, w.w, a3.w);
        }
    }
    *(float4*)(H2 + (size_t)r0 * 40 + cg * 4) = a0;
    if (r0 + 1 < n) *(float4*)(H2 + (size_t)(r0 + 1) * 40 + cg * 4) = a1;
    if (r0 + 2 < n) *(float4*)(H2 + (size_t)(r0 + 2) * 40 + cg * 4) = a2;
    if (r0 + 3 < n) *(float4*)(H2 + (size_t)(r0 + 3) * 40 + cg * 4) = a3;
}

// ---------------- agg2 + bias + log_softmax fused: one wave per node ----------------

__global__ __launch_bounds__(256) void k_agg2(const float* __restrict__ H2,
                                              const float* __restrict__ dinv,
                                              const int* __restrict__ rp,
                                              const int* __restrict__ csrc,
                                              const float* __restrict__ b2,
                                              float* __restrict__ out, int n) {
    int i = blockIdx.x * 4 + (threadIdx.x >> 6);
    if (i >= n) return;
    int lane = threadIdx.x & 63;
    int c = lane < 40 ? lane : 39;  // clamp for loads; lanes >=40 masked at the end
    float di = dinv[i];
    float acc = H2[(size_t)i * 40 + c] * di * di;
    int e = rp[i], end = rp[i + 1];
    for (; e + 1 < end; e += 2) {
        int sA = csrc[e], sB = csrc[e + 1];
        float cA = dinv[sA] * di, cB = dinv[sB] * di;
        acc = fmaf(H2[(size_t)sA * 40 + c], cA, acc);
        acc = fmaf(H2[(size_t)sB * 40 + c], cB, acc);
    }
    if (e < end) {
        int sA = csrc[e];
        acc = fmaf(H2[(size_t)sA * 40 + c], dinv[sA] * di, acc);
    }
    float val = acc + b2[c];
    float m = (lane < 40) ? val : -INFINITY;
#pragma unroll
    for (int off = 32; off; off >>= 1) m = fmaxf(m, __shfl_xor(m, off));
    float ex = (lane < 40) ? expf(val - m) : 0.f;
    float s = ex;
#pragma unroll
    for (int off = 32; off; off >>= 1) s += __shfl_xor(s, off);
    float ls = logf(s);
    if (lane < 40) out[(size_t)i * 40 + lane] = val - m - ls;
}

// ---------------- launch ----------------

extern "C" void kernel_launch(void* const* d_in, const int* in_sizes, int n_in,
                              void* d_out, int out_size, void* d_ws, size_t ws_size,
                              hipStream_t stream) {
    const float* x  = (const float*)d_in[0];
    const int*   ei = (const int*)d_in[1];
    const float* W1 = (const float*)d_in[2];
    const float* b1 = (const float*)d_in[3];
    const float* W2 = (const float*)d_in[4];
    const float* b2 = (const float*)d_in[5];

    int n = in_sizes[0] / 128;
    int E = in_sizes[1] / 2;
    const int* src = ei;
    const int* dst = ei + E;

    float* out = (float*)d_out;

    // workspace layout (4-byte elements, 16B-aligned chunks)
    char* wsb = (char*)d_ws;
    size_t off = 0;
    auto alloc = [&](size_t elems) {
        size_t o = off;
        off += ((elems + 3) & ~(size_t)3) * 4;
        return o;
    };
    float* dinv = (float*)(wsb + alloc(n));
    int* cnt    = (int*)(wsb + alloc(n));
    int* rp     = (int*)(wsb + alloc(n + 1));
    int* nxt    = (int*)(wsb + alloc(n));
    int* bsum   = (int*)(wsb + alloc(256));
    int* csrc   = (int*)(wsb + alloc(E));
    float* bufA = (float*)(wsb + alloc((size_t)n * 128));  // H1, later H2 (n*40)
    float* bufB = (float*)(wsb + alloc((size_t)n * 128));  // relu(h1)

    int nbN = (n + TPB - 1) / TPB;   // blocks over nodes (must be <= 256 for scan_top)
    int nbE = (E + TPB - 1) / TPB;

    k_zero<<<nbN, TPB, 0, stream>>>(cnt, n);
    k_hist<<<nbE, TPB, 0, stream>>>(dst, cnt, E);
    k_scan_block<<<nbN, TPB, 0, stream>>>(cnt, rp, bsum, n);
    k_scan_top<<<1, TPB, 0, stream>>>(bsum, nbN);
    k_scan_add<<<nbN, TPB, 0, stream>>>(rp, bsum, n);
    k_prep<<<nbN, TPB, 0, stream>>>(cnt, rp, nxt, dinv, n);
    k_fill<<<nbE, TPB, 0, stream>>>(src, dst, nxt, csrc, E);

    k_gemm1<<<(n + 31) / 32, TPB, 0, stream>>>(x, W1, bufA, n);
    k_agg1<<<(n + 3) / 4, TPB, 0, stream>>>(bufA, dinv, rp, csrc, b1, bufB, n);
    k_gemm2<<<(n + 99) / 100, TPB, 0, stream>>>(bufB, W2, bufA, n);
    k_agg2<<<(n + 3) / 4, TPB, 0, stream>>>(bufA, dinv, rp, csrc, b2, out, n);
}

// Round 3
// 265.912 us; speedup vs baseline: 2.9928x; 1.1202x over previous
//
#include <hip/hip_runtime.h>
#include <math.h>

static constexpr int TPB = 256;

// ---------------- CSR build ----------------

__global__ void k_zero(int* p, int n) {
    int i = blockIdx.x * TPB + threadIdx.x;
    if (i < n) p[i] = 0;
}

__global__ void k_hist(const int* __restrict__ dst, int* __restrict__ cnt, int E) {
    int e = blockIdx.x * TPB + threadIdx.x;
    if (e < E) atomicAdd(&cnt[dst[e]], 1);
}

// per-block inclusive scan of cnt -> rp[i+1]; block totals -> bsum
__global__ void k_scan_block(const int* __restrict__ cnt, int* __restrict__ rp,
                             int* __restrict__ bsum, int n) {
    __shared__ int s[TPB];
    int t = threadIdx.x;
    int i = blockIdx.x * TPB + t;
    int v = (i < n) ? cnt[i] : 0;
    s[t] = v;
    __syncthreads();
    for (int off = 1; off < TPB; off <<= 1) {
        int a = (t >= off) ? s[t - off] : 0;
        __syncthreads();
        s[t] += a;
        __syncthreads();
    }
    if (i < n) rp[i + 1] = s[t];
    if (t == TPB - 1) bsum[blockIdx.x] = s[t];
}

// exclusive scan of block sums (nb <= 256)
__global__ void k_scan_top(int* bsum, int nb) {
    __shared__ int s[TPB];
    int t = threadIdx.x;
    int v = (t < nb) ? bsum[t] : 0;
    s[t] = v;
    __syncthreads();
    for (int off = 1; off < TPB; off <<= 1) {
        int a = (t >= off) ? s[t - off] : 0;
        __syncthreads();
        s[t] += a;
        __syncthreads();
    }
    if (t < nb) bsum[t] = s[t] - v;  // exclusive
}

__global__ void k_scan_add(int* rp, const int* __restrict__ bsum, int n) {
    int i = blockIdx.x * TPB + threadIdx.x;
    if (i < n) rp[i + 1] += bsum[i >> 8];
    if (i == 0) rp[0] = 0;
}

// nxt[i] = rp[i] (allocation cursor), dinv[i] = rsqrt(1+deg)
__global__ void k_prep(const int* __restrict__ cnt, const int* __restrict__ rp,
                       int* __restrict__ nxt, float* __restrict__ dinv, int n) {
    int i = blockIdx.x * TPB + threadIdx.x;
    if (i < n) {
        nxt[i] = rp[i];
        dinv[i] = rsqrtf(1.0f + (float)cnt[i]);
    }
}

__global__ void k_fill(const int* __restrict__ src, const int* __restrict__ dst, int* nxt,
                       int* __restrict__ csrc, int E) {
    int e = blockIdx.x * TPB + threadIdx.x;
    if (e < E) {
        int d = dst[e];
        int pos = atomicAdd(&nxt[d], 1);
        csrc[pos] = src[e];
    }
}

// ---------------- GEMM1: H' = (x @ W1) * dinv[row]  (128x128), 4x4 micro-tile ----------------

#define COMP(v, j) ((j) == 0 ? (v).x : ((j) == 1 ? (v).y : ((j) == 2 ? (v).z : (v).w)))

__device__ inline float4 scale4(float4 a, float s) {
    a.x *= s; a.y *= s; a.z *= s; a.w *= s;
    return a;
}

__global__ __launch_bounds__(256) void k_gemm1(const float* __restrict__ x,
                                               const float* __restrict__ W,
                                               const float* __restrict__ dinv,
                                               float* __restrict__ H, int n) {
    __shared__ float Wl[128 * 128];  // 64 KiB
    {
        const float4* W4 = (const float4*)W;
        float4* L4 = (float4*)Wl;
        for (int i = threadIdx.x; i < 128 * 32; i += TPB) L4[i] = W4[i];
    }
    __syncthreads();
    int t = threadIdx.x;
    int cg = t & 31;                         // col group: cols cg*4 .. cg*4+3
    int r0 = blockIdx.x * 32 + (t >> 5) * 4; // 4 rows per thread, 32 rows per block
    if (r0 >= n) return;
    int r1 = min(r0 + 1, n - 1), r2 = min(r0 + 2, n - 1), r3 = min(r0 + 3, n - 1);
    const float* x0 = x + (size_t)r0 * 128;
    const float* x1 = x + (size_t)r1 * 128;
    const float* x2 = x + (size_t)r2 * 128;
    const float* x3 = x + (size_t)r3 * 128;
    float4 a0 = make_float4(0, 0, 0, 0), a1 = a0, a2 = a0, a3 = a0;
    const float4* L4 = (const float4*)Wl;
    for (int k = 0; k < 128; k += 4) {
        float4 xa = *(const float4*)(x0 + k);
        float4 xb = *(const float4*)(x1 + k);
        float4 xc = *(const float4*)(x2 + k);
        float4 xd = *(const float4*)(x3 + k);
#pragma unroll
        for (int j = 0; j < 4; ++j) {
            float4 w = L4[(k + j) * 32 + cg];
            float va = COMP(xa, j), vb = COMP(xb, j), vc = COMP(xc, j), vd = COMP(xd, j);
            a0.x = fmaf(va, w.x, a0.x); a0.y = fmaf(va, w.y, a0.y);
            a0.z = fmaf(va, w.z, a0.z); a0.w = fmaf(va, w.w, a0.w);
            a1.x = fmaf(vb, w.x, a1.x); a1.y = fmaf(vb, w.y, a1.y);
            a1.z = fmaf(vb, w.z, a1.z); a1.w = fmaf(vb, w.w, a1.w);
            a2.x = fmaf(vc, w.x, a2.x); a2.y = fmaf(vc, w.y, a2.y);
            a2.z = fmaf(vc, w.z, a2.z); a2.w = fmaf(vc, w.w, a2.w);
            a3.x = fmaf(vd, w.x, a3.x); a3.y = fmaf(vd, w.y, a3.y);
            a3.z = fmaf(vd, w.z, a3.z); a3.w = fmaf(vd, w.w, a3.w);
        }
    }
    *(float4*)(H + (size_t)r0 * 128 + cg * 4) = scale4(a0, dinv[r0]);
    if (r0 + 1 < n) *(float4*)(H + (size_t)(r0 + 1) * 128 + cg * 4) = scale4(a1, dinv[r1]);
    if (r0 + 2 < n) *(float4*)(H + (size_t)(r0 + 2) * 128 + cg * 4) = scale4(a2, dinv[r2]);
    if (r0 + 3 < n) *(float4*)(H + (size_t)(r0 + 3) * 128 + cg * 4) = scale4(a3, dinv[r3]);
}

// ---------------- agg1: h = relu( dinv[i] * (H'[i] + sum_in H'[s]) + b1 ) ----------------

__global__ __launch_bounds__(256) void k_agg1(const float* __restrict__ H,
                                              const int* __restrict__ rp,
                                              const int* __restrict__ csrc,
                                              const float* __restrict__ dinv,
                                              const float* __restrict__ b1,
                                              float* __restrict__ hout, int n) {
    int i = blockIdx.x * 4 + (threadIdx.x >> 6);
    if (i >= n) return;
    int lane = threadIdx.x & 63;
    const float2* Hv = (const float2*)H;
    float2 s0 = Hv[(size_t)i * 64 + lane];  // self message
    float2 s1 = make_float2(0.f, 0.f), s2 = s1, s3 = s1;
    int e = rp[i], end = rp[i + 1];
    for (; e + 8 <= end; e += 8) {
        int i0 = csrc[e], i1 = csrc[e + 1], i2 = csrc[e + 2], i3 = csrc[e + 3];
        int i4 = csrc[e + 4], i5 = csrc[e + 5], i6 = csrc[e + 6], i7 = csrc[e + 7];
        float2 v0 = Hv[(size_t)i0 * 64 + lane];
        float2 v1 = Hv[(size_t)i1 * 64 + lane];
        float2 v2 = Hv[(size_t)i2 * 64 + lane];
        float2 v3 = Hv[(size_t)i3 * 64 + lane];
        float2 v4 = Hv[(size_t)i4 * 64 + lane];
        float2 v5 = Hv[(size_t)i5 * 64 + lane];
        float2 v6 = Hv[(size_t)i6 * 64 + lane];
        float2 v7 = Hv[(size_t)i7 * 64 + lane];
        s0.x += v0.x; s0.y += v0.y;
        s1.x += v1.x; s1.y += v1.y;
        s2.x += v2.x; s2.y += v2.y;
        s3.x += v3.x; s3.y += v3.y;
        s0.x += v4.x; s0.y += v4.y;
        s1.x += v5.x; s1.y += v5.y;
        s2.x += v6.x; s2.y += v6.y;
        s3.x += v7.x; s3.y += v7.y;
    }
    for (; e + 2 <= end; e += 2) {
        int i0 = csrc[e], i1 = csrc[e + 1];
        float2 v0 = Hv[(size_t)i0 * 64 + lane];
        float2 v1 = Hv[(size_t)i1 * 64 + lane];
        s0.x += v0.x; s0.y += v0.y;
        s1.x += v1.x; s1.y += v1.y;
    }
    if (e < end) {
        int i0 = csrc[e];
        float2 v0 = Hv[(size_t)i0 * 64 + lane];
        s0.x += v0.x; s0.y += v0.y;
    }
    float di = dinv[i];
    float2 bb = ((const float2*)b1)[lane];
    float2 r;
    r.x = fmaxf(fmaf((s0.x + s1.x) + (s2.x + s3.x), di, bb.x), 0.f);
    r.y = fmaxf(fmaf((s0.y + s1.y) + (s2.y + s3.y), di, bb.y), 0.f);
    ((float2*)hout)[(size_t)i * 64 + lane] = r;
}

// ---------------- GEMM2: H2' = (h @ W2) * dinv[row]  (128x40) ----------------

__global__ __launch_bounds__(256) void k_gemm2(const float* __restrict__ h,
                                               const float* __restrict__ W,
                                               const float* __restrict__ dinv,
                                               float* __restrict__ H2, int n) {
    __shared__ float Wl[128 * 40];  // 20 KiB
    {
        const float4* W4 = (const float4*)W;
        float4* L4 = (float4*)Wl;
        for (int i = threadIdx.x; i < 128 * 10; i += TPB) L4[i] = W4[i];
    }
    __syncthreads();
    int t = threadIdx.x;
    if (t >= 250) return;
    int cg = t % 10;  // col group: cols cg*4 .. cg*4+3
    int rb = t / 10;
    int r0 = blockIdx.x * 100 + rb * 4;
    if (r0 >= n) return;
    int r1 = min(r0 + 1, n - 1), r2 = min(r0 + 2, n - 1), r3 = min(r0 + 3, n - 1);
    const float* h0 = h + (size_t)r0 * 128;
    const float* h1 = h + (size_t)r1 * 128;
    const float* h2 = h + (size_t)r2 * 128;
    const float* h3 = h + (size_t)r3 * 128;
    float4 a0 = make_float4(0, 0, 0, 0), a1 = a0, a2 = a0, a3 = a0;
    const float4* L4 = (const float4*)Wl;
    for (int k = 0; k < 128; k += 4) {
        float4 xa = *(const float4*)(h0 + k);
        float4 xb = *(const float4*)(h1 + k);
        float4 xc = *(const float4*)(h2 + k);
        float4 xd = *(const float4*)(h3 + k);
#pragma unroll
        for (int j = 0; j < 4; ++j) {
            float4 w = L4[(k + j) * 10 + cg];
            float va = COMP(xa, j), vb = COMP(xb, j), vc = COMP(xc, j), vd = COMP(xd, j);
            a0.x = fmaf(va, w.x, a0.x); a0.y = fmaf(va, w.y, a0.y);
            a0.z = fmaf(va, w.z, a0.z); a0.w = fmaf(va, w.w, a0.w);
            a1.x = fmaf(vb, w.x, a1.x); a1.y = fmaf(vb, w.y, a1.y);
            a1.z = fmaf(vb, w.z, a1.z); a1.w = fmaf(vb, w.w, a1.w);
            a2.x = fmaf(vc, w.x, a2.x); a2.y = fmaf(vc, w.y, a2.y);
            a2.z = fmaf(vc, w.z, a2.z); a2.w = fmaf(vc, w.w, a2.w);
            a3.x = fmaf(vd, w.x, a3.x); a3.y = fmaf(vd, w.y, a3.y);
            a3.z = fmaf(vd, w.z, a3.z); a3.w = fmaf(vd, w.w, a3.w);
        }
    }
    *(float4*)(H2 + (size_t)r0 * 40 + cg * 4) = scale4(a0, dinv[r0]);
    if (r0 + 1 < n) *(float4*)(H2 + (size_t)(r0 + 1) * 40 + cg * 4) = scale4(a1, dinv[r1]);
    if (r0 + 2 < n) *(float4*)(H2 + (size_t)(r0 + 2) * 40 + cg * 4) = scale4(a2, dinv[r2]);
    if (r0 + 3 < n) *(float4*)(H2 + (size_t)(r0 + 3) * 40 + cg * 4) = scale4(a3, dinv[r3]);
}

// ---------------- agg2 + bias + log_softmax fused: one wave per node ----------------

__global__ __launch_bounds__(256) void k_agg2(const float* __restrict__ H2,
                                              const int* __restrict__ rp,
                                              const int* __restrict__ csrc,
                                              const float* __restrict__ dinv,
                                              const float* __restrict__ b2,
                                              float* __restrict__ out, int n) {
    int i = blockIdx.x * 4 + (threadIdx.x >> 6);
    if (i >= n) return;
    int lane = threadIdx.x & 63;
    int c = lane < 40 ? lane : 39;  // clamp for loads; lanes >=40 masked at the end
    float s0 = H2[(size_t)i * 40 + c];  // self message
    float s1 = 0.f, s2 = 0.f, s3 = 0.f;
    int e = rp[i], end = rp[i + 1];
    for (; e + 8 <= end; e += 8) {
        int i0 = csrc[e], i1 = csrc[e + 1], i2 = csrc[e + 2], i3 = csrc[e + 3];
        int i4 = csrc[e + 4], i5 = csrc[e + 5], i6 = csrc[e + 6], i7 = csrc[e + 7];
        float v0 = H2[(size_t)i0 * 40 + c];
        float v1 = H2[(size_t)i1 * 40 + c];
        float v2 = H2[(size_t)i2 * 40 + c];
        float v3 = H2[(size_t)i3 * 40 + c];
        float v4 = H2[(size_t)i4 * 40 + c];
        float v5 = H2[(size_t)i5 * 40 + c];
        float v6 = H2[(size_t)i6 * 40 + c];
        float v7 = H2[(size_t)i7 * 40 + c];
        s0 += v0; s1 += v1; s2 += v2; s3 += v3;
        s0 += v4; s1 += v5; s2 += v6; s3 += v7;
    }
    for (; e + 2 <= end; e += 2) {
        int i0 = csrc[e], i1 = csrc[e + 1];
        s0 += H2[(size_t)i0 * 40 + c];
        s1 += H2[(size_t)i1 * 40 + c];
    }
    if (e < end) s0 += H2[(size_t)csrc[e] * 40 + c];
    float di = dinv[i];
    float val = fmaf((s0 + s1) + (s2 + s3), di, b2[c]);
    float m = (lane < 40) ? val : -INFINITY;
#pragma unroll
    for (int off = 32; off; off >>= 1) m = fmaxf(m, __shfl_xor(m, off));
    float ex = (lane < 40) ? expf(val - m) : 0.f;
    float s = ex;
#pragma unroll
    for (int off = 32; off; off >>= 1) s += __shfl_xor(s, off);
    float ls = logf(s);
    if (lane < 40) out[(size_t)i * 40 + lane] = val - m - ls;
}

// ---------------- launch ----------------

extern "C" void kernel_launch(void* const* d_in, const int* in_sizes, int n_in,
                              void* d_out, int out_size, void* d_ws, size_t ws_size,
                              hipStream_t stream) {
    const float* x  = (const float*)d_in[0];
    const int*   ei = (const int*)d_in[1];
    const float* W1 = (const float*)d_in[2];
    const float* b1 = (const float*)d_in[3];
    const float* W2 = (const float*)d_in[4];
    const float* b2 = (const float*)d_in[5];

    int n = in_sizes[0] / 128;
    int E = in_sizes[1] / 2;
    const int* src = ei;
    const int* dst = ei + E;

    float* out = (float*)d_out;

    // workspace layout (4-byte elements, 16B-aligned chunks)
    char* wsb = (char*)d_ws;
    size_t off = 0;
    auto alloc = [&](size_t elems) {
        size_t o = off;
        off += ((elems + 3) & ~(size_t)3) * 4;
        return o;
    };
    float* dinv = (float*)(wsb + alloc(n));
    int* cnt    = (int*)(wsb + alloc(n));
    int* rp     = (int*)(wsb + alloc(n + 1));
    int* nxt    = (int*)(wsb + alloc(n));
    int* bsum   = (int*)(wsb + alloc(256));
    int* csrc   = (int*)(wsb + alloc(E));
    float* bufA = (float*)(wsb + alloc((size_t)n * 128));  // H1', later H2' (n*40)
    float* bufB = (float*)(wsb + alloc((size_t)n * 128));  // relu(h1)

    int nbN = (n + TPB - 1) / TPB;   // blocks over nodes (must be <= 256 for scan_top)
    int nbE = (E + TPB - 1) / TPB;

    k_zero<<<nbN, TPB, 0, stream>>>(cnt, n);
    k_hist<<<nbE, TPB, 0, stream>>>(dst, cnt, E);
    k_scan_block<<<nbN, TPB, 0, stream>>>(cnt, rp, bsum, n);
    k_scan_top<<<1, TPB, 0, stream>>>(bsum, nbN);
    k_scan_add<<<nbN, TPB, 0, stream>>>(rp, bsum, n);
    k_prep<<<nbN, TPB, 0, stream>>>(cnt, rp, nxt, dinv, n);
    k_fill<<<nbE, TPB, 0, stream>>>(src, dst, nxt, csrc, E);

    k_gemm1<<<(n + 31) / 32, TPB, 0, stream>>>(x, W1, dinv, bufA, n);
    k_agg1<<<(n + 3) / 4, TPB, 0, stream>>>(bufA, rp, csrc, dinv, b1, bufB, n);
    k_gemm2<<<(n + 99) / 100, TPB, 0, stream>>>(bufB, W2, dinv, bufA, n);
    k_agg2<<<(n + 3) / 4, TPB, 0, stream>>>(bufA, rp, csrc, dinv, b2, out, n);
}

// Round 7
// 229.259 us; speedup vs baseline: 3.4712x; 1.1599x over previous
//
#include <hip/hip_runtime.h>
#include <math.h>

static constexpr int TPB = 256;

// float -> bf16 (round-to-nearest-even), finite inputs
__device__ inline unsigned short f2bf(float f) {
    unsigned u = __float_as_uint(f);
    return (unsigned short)((u + 0x7fffu + ((u >> 16) & 1u)) >> 16);
}
__device__ inline float bf2f(unsigned short b) {
    return __uint_as_float(((unsigned)b) << 16);
}

// ---------------- CSR build ----------------

__global__ void k_zero(int* p, int n) {
    int i = blockIdx.x * TPB + threadIdx.x;
    if (i < n) p[i] = 0;
}

__global__ void k_hist(const int* __restrict__ dst, int* __restrict__ cnt, int E) {
    int e = blockIdx.x * TPB + threadIdx.x;
    if (e < E) atomicAdd(&cnt[dst[e]], 1);
}

// per-block inclusive scan of cnt -> rp[i+1]; block totals -> bsum
__global__ void k_scan_block(const int* __restrict__ cnt, int* __restrict__ rp,
                             int* __restrict__ bsum, int n) {
    __shared__ int s[TPB];
    int t = threadIdx.x;
    int i = blockIdx.x * TPB + t;
    int v = (i < n) ? cnt[i] : 0;
    s[t] = v;
    __syncthreads();
    for (int off = 1; off < TPB; off <<= 1) {
        int a = (t >= off) ? s[t - off] : 0;
        __syncthreads();
        s[t] += a;
        __syncthreads();
    }
    if (i < n) rp[i + 1] = s[t];
    if (t == TPB - 1) bsum[blockIdx.x] = s[t];
}

// exclusive scan of block sums (nb <= 256)
__global__ void k_scan_top(int* bsum, int nb) {
    __shared__ int s[TPB];
    int t = threadIdx.x;
    int v = (t < nb) ? bsum[t] : 0;
    s[t] = v;
    __syncthreads();
    for (int off = 1; off < TPB; off <<= 1) {
        int a = (t >= off) ? s[t - off] : 0;
        __syncthreads();
        s[t] += a;
        __syncthreads();
    }
    if (t < nb) bsum[t] = s[t] - v;  // exclusive
}

// rp finalize + allocation cursor + dinv, fused
__global__ void k_scan_add_prep(int* rp, const int* __restrict__ bsum,
                                const int* __restrict__ cnt, int* __restrict__ nxt,
                                float* __restrict__ dinv, int n) {
    int i = blockIdx.x * TPB + threadIdx.x;
    if (i < n) {
        int incl = rp[i + 1] + bsum[i >> 8];
        rp[i + 1] = incl;
        int c = cnt[i];
        nxt[i] = incl - c;  // = rp[i]
        dinv[i] = rsqrtf(1.0f + (float)c);
    }
    if (i == 0) rp[0] = 0;
}

__global__ void k_fill(const int* __restrict__ src, const int* __restrict__ dst, int* nxt,
                       int* __restrict__ csrc, int E) {
    int e = blockIdx.x * TPB + threadIdx.x;
    if (e < E) {
        int d = dst[e];
        int pos = atomicAdd(&nxt[d], 1);
        csrc[pos] = src[e];
    }
}

// ---------------- GEMM1: Hb = bf16( (x @ W1) * dinv[row] )  (128x128) ----------------

#define COMP(v, j) ((j) == 0 ? (v).x : ((j) == 1 ? (v).y : ((j) == 2 ? (v).z : (v).w)))

__global__ __launch_bounds__(256) void k_gemm1(const float* __restrict__ x,
                                               const float* __restrict__ W,
                                               const float* __restrict__ dinv,
                                               unsigned short* __restrict__ Hb, int n) {
    __shared__ float Wl[128 * 128];  // 64 KiB
    {
        const float4* W4 = (const float4*)W;
        float4* L4 = (float4*)Wl;
        for (int i = threadIdx.x; i < 128 * 32; i += TPB) L4[i] = W4[i];
    }
    __syncthreads();
    int t = threadIdx.x;
    int cg = t & 31;                         // col group: cols cg*4 .. cg*4+3
    int r0 = blockIdx.x * 32 + (t >> 5) * 4; // 4 rows per thread, 32 rows per block
    if (r0 >= n) return;
    int r1 = min(r0 + 1, n - 1), r2 = min(r0 + 2, n - 1), r3 = min(r0 + 3, n - 1);
    const float* x0 = x + (size_t)r0 * 128;
    const float* x1 = x + (size_t)r1 * 128;
    const float* x2 = x + (size_t)r2 * 128;
    const float* x3 = x + (size_t)r3 * 128;
    float4 a0 = make_float4(0, 0, 0, 0), a1 = a0, a2 = a0, a3 = a0;
    const float4* L4 = (const float4*)Wl;
    for (int k = 0; k < 128; k += 4) {
        float4 xa = *(const float4*)(x0 + k);
        float4 xb = *(const float4*)(x1 + k);
        float4 xc = *(const float4*)(x2 + k);
        float4 xd = *(const float4*)(x3 + k);
#pragma unroll
        for (int j = 0; j < 4; ++j) {
            float4 w = L4[(k + j) * 32 + cg];
            float va = COMP(xa, j), vb = COMP(xb, j), vc = COMP(xc, j), vd = COMP(xd, j);
            a0.x = fmaf(va, w.x, a0.x); a0.y = fmaf(va, w.y, a0.y);
            a0.z = fmaf(va, w.z, a0.z); a0.w = fmaf(va, w.w, a0.w);
            a1.x = fmaf(vb, w.x, a1.x); a1.y = fmaf(vb, w.y, a1.y);
            a1.z = fmaf(vb, w.z, a1.z); a1.w = fmaf(vb, w.w, a1.w);
            a2.x = fmaf(vc, w.x, a2.x); a2.y = fmaf(vc, w.y, a2.y);
            a2.z = fmaf(vc, w.z, a2.z); a2.w = fmaf(vc, w.w, a2.w);
            a3.x = fmaf(vd, w.x, a3.x); a3.y = fmaf(vd, w.y, a3.y);
            a3.z = fmaf(vd, w.z, a3.z); a3.w = fmaf(vd, w.w, a3.w);
        }
    }
    auto store = [&](int r, float4 a) {
        float s = dinv[r];
        ushort4 o;
        o.x = f2bf(a.x * s); o.y = f2bf(a.y * s); o.z = f2bf(a.z * s); o.w = f2bf(a.w * s);
        *(ushort4*)(Hb + (size_t)r * 128 + cg * 4) = o;
    };
    store(r0, a0);
    if (r0 + 1 < n) store(r0 + 1, a1);
    if (r0 + 2 < n) store(r0 + 2, a2);
    if (r0 + 3 < n) store(r0 + 3, a3);
}

// ---------------- agg1: h = relu( dinv[i] * (Hb[i] + sum_in Hb[s]) + b1 ) ----------------
// Hb rows are 128 bf16 = 64 uint32; lane handles features 2*lane, 2*lane+1.

__global__ __launch_bounds__(256) void k_agg1(const unsigned int* __restrict__ Hb32,
                                              const int* __restrict__ rp,
                                              const int* __restrict__ csrc,
                                              const float* __restrict__ dinv,
                                              const float* __restrict__ b1,
                                              float* __restrict__ hout, int n) {
    int i = blockIdx.x * 4 + (threadIdx.x >> 6);
    if (i >= n) return;
    int lane = threadIdx.x & 63;
    unsigned vself = Hb32[(size_t)i * 64 + lane];
    float s0x = __uint_as_float(vself << 16);
    float s0y = __uint_as_float(vself & 0xffff0000u);
    float s1x = 0.f, s1y = 0.f, s2x = 0.f, s2y = 0.f, s3x = 0.f, s3y = 0.f;
    int e = rp[i], end = rp[i + 1];
    for (; e + 8 <= end; e += 8) {
        int i0 = csrc[e], i1 = csrc[e + 1], i2 = csrc[e + 2], i3 = csrc[e + 3];
        int i4 = csrc[e + 4], i5 = csrc[e + 5], i6 = csrc[e + 6], i7 = csrc[e + 7];
        unsigned v0 = Hb32[(size_t)i0 * 64 + lane];
        unsigned v1 = Hb32[(size_t)i1 * 64 + lane];
        unsigned v2 = Hb32[(size_t)i2 * 64 + lane];
        unsigned v3 = Hb32[(size_t)i3 * 64 + lane];
        unsigned v4 = Hb32[(size_t)i4 * 64 + lane];
        unsigned v5 = Hb32[(size_t)i5 * 64 + lane];
        unsigned v6 = Hb32[(size_t)i6 * 64 + lane];
        unsigned v7 = Hb32[(size_t)i7 * 64 + lane];
        s0x += __uint_as_float(v0 << 16); s0y += __uint_as_float(v0 & 0xffff0000u);
        s1x += __uint_as_float(v1 << 16); s1y += __uint_as_float(v1 & 0xffff0000u);
        s2x += __uint_as_float(v2 << 16); s2y += __uint_as_float(v2 & 0xffff0000u);
        s3x += __uint_as_float(v3 << 16); s3y += __uint_as_float(v3 & 0xffff0000u);
        s0x += __uint_as_float(v4 << 16); s0y += __uint_as_float(v4 & 0xffff0000u);
        s1x += __uint_as_float(v5 << 16); s1y += __uint_as_float(v5 & 0xffff0000u);
        s2x += __uint_as_float(v6 << 16); s2y += __uint_as_float(v6 & 0xffff0000u);
        s3x += __uint_as_float(v7 << 16); s3y += __uint_as_float(v7 & 0xffff0000u);
    }
    for (; e + 2 <= end; e += 2) {
        int i0 = csrc[e], i1 = csrc[e + 1];
        unsigned v0 = Hb32[(size_t)i0 * 64 + lane];
        unsigned v1 = Hb32[(size_t)i1 * 64 + lane];
        s0x += __uint_as_float(v0 << 16); s0y += __uint_as_float(v0 & 0xffff0000u);
        s1x += __uint_as_float(v1 << 16); s1y += __uint_as_float(v1 & 0xffff0000u);
    }
    if (e < end) {
        unsigned v0 = Hb32[(size_t)csrc[e] * 64 + lane];
        s0x += __uint_as_float(v0 << 16); s0y += __uint_as_float(v0 & 0xffff0000u);
    }
    float di = dinv[i];
    float2 bb = ((const float2*)b1)[lane];
    float2 r;
    r.x = fmaxf(fmaf((s0x + s1x) + (s2x + s3x), di, bb.x), 0.f);
    r.y = fmaxf(fmaf((s0y + s1y) + (s2y + s3y), di, bb.y), 0.f);
    ((float2*)hout)[(size_t)i * 64 + lane] = r;
}

// ---------------- GEMM2: H2b = bf16( (h @ W2) * dinv[row] )  (128x40) ----------------

__global__ __launch_bounds__(256) void k_gemm2(const float* __restrict__ h,
                                               const float* __restrict__ W,
                                               const float* __restrict__ dinv,
                                               unsigned short* __restrict__ H2b, int n) {
    __shared__ float Wl[128 * 40];  // 20 KiB
    {
        const float4* W4 = (const float4*)W;
        float4* L4 = (float4*)Wl;
        for (int i = threadIdx.x; i < 128 * 10; i += TPB) L4[i] = W4[i];
    }
    __syncthreads();
    int t = threadIdx.x;
    if (t >= 250) return;
    int cg = t % 10;  // col group: cols cg*4 .. cg*4+3
    int rb = t / 10;
    int r0 = blockIdx.x * 100 + rb * 4;
    if (r0 >= n) return;
    int r1 = min(r0 + 1, n - 1), r2 = min(r0 + 2, n - 1), r3 = min(r0 + 3, n - 1);
    const float* h0 = h + (size_t)r0 * 128;
    const float* h1 = h + (size_t)r1 * 128;
    const float* h2 = h + (size_t)r2 * 128;
    const float* h3 = h + (size_t)r3 * 128;
    float4 a0 = make_float4(0, 0, 0, 0), a1 = a0, a2 = a0, a3 = a0;
    const float4* L4 = (const float4*)Wl;
    for (int k = 0; k < 128; k += 4) {
        float4 xa = *(const float4*)(h0 + k);
        float4 xb = *(const float4*)(h1 + k);
        float4 xc = *(const float4*)(h2 + k);
        float4 xd = *(const float4*)(h3 + k);
#pragma unroll
        for (int j = 0; j < 4; ++j) {
            float4 w = L4[(k + j) * 10 + cg];
            float va = COMP(xa, j), vb = COMP(xb, j), vc = COMP(xc, j), vd = COMP(xd, j);
            a0.x = fmaf(va, w.x, a0.x); a0.y = fmaf(va, w.y, a0.y);
            a0.z = fmaf(va, w.z, a0.z); a0.w = fmaf(va, w.w, a0.w);
            a1.x = fmaf(vb, w.x, a1.x); a1.y = fmaf(vb, w.y, a1.y);
            a1.z = fmaf(vb, w.z, a1.z); a1.w = fmaf(vb, w.w, a1.w);
            a2.x = fmaf(vc, w.x, a2.x); a2.y = fmaf(vc, w.y, a2.y);
            a2.z = fmaf(vc, w.z, a2.z); a2.w = fmaf(vc, w.w, a2.w);
            a3.x = fmaf(vd, w.x, a3.x); a3.y = fmaf(vd, w.y, a3.y);
            a3.z = fmaf(vd, w.z, a3.z); a3.w = fmaf(vd, w.w, a3.w);
        }
    }
    auto store = [&](int r, float4 a) {
        float s = dinv[r];
        ushort4 o;
        o.x = f2bf(a.x * s); o.y = f2bf(a.y * s); o.z = f2bf(a.z * s); o.w = f2bf(a.w * s);
        *(ushort4*)(H2b + (size_t)r * 40 + cg * 4) = o;
    };
    store(r0, a0);
    if (r0 + 1 < n) store(r0 + 1, a1);
    if (r0 + 2 < n) store(r0 + 2, a2);
    if (r0 + 3 < n) store(r0 + 3, a3);
}

// ---------------- agg2 + bias + log_softmax fused: one wave per node ----------------

__global__ __launch_bounds__(256) void k_agg2(const unsigned short* __restrict__ H2b,
                                              const int* __restrict__ rp,
                                              const int* __restrict__ csrc,
                                              const float* __restrict__ dinv,
                                              const float* __restrict__ b2,
                                              float* __restrict__ out, int n) {
    int i = blockIdx.x * 4 + (threadIdx.x >> 6);
    if (i >= n) return;
    int lane = threadIdx.x & 63;
    int c = lane < 40 ? lane : 39;  // clamp for loads; lanes >=40 masked at the end
    float s0 = bf2f(H2b[(size_t)i * 40 + c]);  // self message
    float s1 = 0.f, s2 = 0.f, s3 = 0.f;
    int e = rp[i], end = rp[i + 1];
    for (; e + 8 <= end; e += 8) {
        int i0 = csrc[e], i1 = csrc[e + 1], i2 = csrc[e + 2], i3 = csrc[e + 3];
        int i4 = csrc[e + 4], i5 = csrc[e + 5], i6 = csrc[e + 6], i7 = csrc[e + 7];
        float v0 = bf2f(H2b[(size_t)i0 * 40 + c]);
        float v1 = bf2f(H2b[(size_t)i1 * 40 + c]);
        float v2 = bf2f(H2b[(size_t)i2 * 40 + c]);
        float v3 = bf2f(H2b[(size_t)i3 * 40 + c]);
        float v4 = bf2f(H2b[(size_t)i4 * 40 + c]);
        float v5 = bf2f(H2b[(size_t)i5 * 40 + c]);
        float v6 = bf2f(H2b[(size_t)i6 * 40 + c]);
        float v7 = bf2f(H2b[(size_t)i7 * 40 + c]);
        s0 += v0; s1 += v1; s2 += v2; s3 += v3;
        s0 += v4; s1 += v5; s2 += v6; s3 += v7;
    }
    for (; e + 2 <= end; e += 2) {
        s0 += bf2f(H2b[(size_t)csrc[e] * 40 + c]);
        s1 += bf2f(H2b[(size_t)csrc[e + 1] * 40 + c]);
    }
    if (e < end) s0 += bf2f(H2b[(size_t)csrc[e] * 40 + c]);
    float di = dinv[i];
    float val = fmaf((s0 + s1) + (s2 + s3), di, b2[c]);
    float m = (lane < 40) ? val : -INFINITY;
#pragma unroll
    for (int off = 32; off; off >>= 1) m = fmaxf(m, __shfl_xor(m, off));
    float ex = (lane < 40) ? expf(val - m) : 0.f;
    float s = ex;
#pragma unroll
    for (int off = 32; off; off >>= 1) s += __shfl_xor(s, off);
    float ls = logf(s);
    if (lane < 40) out[(size_t)i * 40 + lane] = val - m - ls;
}

// ---------------- launch ----------------

extern "C" void kernel_launch(void* const* d_in, const int* in_sizes, int n_in,
                              void* d_out, int out_size, void* d_ws, size_t ws_size,
                              hipStream_t stream) {
    const float* x  = (const float*)d_in[0];
    const int*   ei = (const int*)d_in[1];
    const float* W1 = (const float*)d_in[2];
    const float* b1 = (const float*)d_in[3];
    const float* W2 = (const float*)d_in[4];
    const float* b2 = (const float*)d_in[5];

    int n = in_sizes[0] / 128;
    int E = in_sizes[1] / 2;
    const int* src = ei;
    const int* dst = ei + E;

    float* out = (float*)d_out;

    // workspace layout (4-byte units, 16B-aligned chunks)
    char* wsb = (char*)d_ws;
    size_t off = 0;
    auto alloc = [&](size_t elems4) {
        size_t o = off;
        off += ((elems4 + 3) & ~(size_t)3) * 4;
        return o;
    };
    float* dinv = (float*)(wsb + alloc(n));
    int* cnt    = (int*)(wsb + alloc(n));
    int* rp     = (int*)(wsb + alloc(n + 1));
    int* nxt    = (int*)(wsb + alloc(n));
    int* bsum   = (int*)(wsb + alloc(256));
    int* csrc   = (int*)(wsb + alloc(E));
    unsigned int* Hb32   = (unsigned int*)(wsb + alloc((size_t)n * 64));   // H1' bf16, 12.8 MB
    float* hout          = (float*)(wsb + alloc((size_t)n * 128));         // relu(h1), 25.6 MB
    unsigned short* H2b  = (unsigned short*)(wsb + alloc((size_t)n * 20)); // H2' bf16, 4 MB

    int nbN = (n + TPB - 1) / TPB;   // must be <= 256 for scan_top (50000/256=196, ok)
    int nbE = (E + TPB - 1) / TPB;

    k_zero<<<nbN, TPB, 0, stream>>>(cnt, n);
    k_hist<<<nbE, TPB, 0, stream>>>(dst, cnt, E);
    k_scan_block<<<nbN, TPB, 0, stream>>>(cnt, rp, bsum, n);
    k_scan_top<<<1, TPB, 0, stream>>>(bsum, nbN);
    k_scan_add_prep<<<nbN, TPB, 0, stream>>>(rp, bsum, cnt, nxt, dinv, n);
    k_fill<<<nbE, TPB, 0, stream>>>(src, dst, nxt, csrc, E);

    k_gemm1<<<(n + 31) / 32, TPB, 0, stream>>>(x, W1, dinv, (unsigned short*)Hb32, n);
    k_agg1<<<(n + 3) / 4, TPB, 0, stream>>>(Hb32, rp, csrc, dinv, b1, hout, n);
    k_gemm2<<<(n + 99) / 100, TPB, 0, stream>>>(hout, W2, dinv, H2b, n);
    k_agg2<<<(n + 3) / 4, TPB, 0, stream>>>(H2b, rp, csrc, dinv, b2, out, n);
}

// Round 8
// 189.819 us; speedup vs baseline: 4.1925x; 1.2078x over previous
//
#include <hip/hip_runtime.h>
#include <math.h>

static constexpr int TPB = 256;

// float -> bf16 (round-to-nearest-even), finite inputs
__device__ inline unsigned short f2bf(float f) {
    unsigned u = __float_as_uint(f);
    return (unsigned short)((u + 0x7fffu + ((u >> 16) & 1u)) >> 16);
}
__device__ inline float bf2f(unsigned short b) {
    return __uint_as_float(((unsigned)b) << 16);
}

// ---------------- CSR build ----------------

__global__ void k_zero(int* p, int n) {
    int i = blockIdx.x * TPB + threadIdx.x;
    if (i < n) p[i] = 0;
}

// histogram + per-edge position within its destination bucket (one atomic pass total)
__global__ void k_hist_pos(const int* __restrict__ dst, int* __restrict__ cnt,
                           int* __restrict__ epos, int E) {
    int e = blockIdx.x * TPB + threadIdx.x;
    if (e < E) epos[e] = atomicAdd(&cnt[dst[e]], 1);
}

// per-block inclusive scan of cnt -> rp[i+1]; block totals -> bsum
__global__ void k_scan_block(const int* __restrict__ cnt, int* __restrict__ rp,
                             int* __restrict__ bsum, int n) {
    __shared__ int s[TPB];
    int t = threadIdx.x;
    int i = blockIdx.x * TPB + t;
    int v = (i < n) ? cnt[i] : 0;
    s[t] = v;
    __syncthreads();
    for (int off = 1; off < TPB; off <<= 1) {
        int a = (t >= off) ? s[t - off] : 0;
        __syncthreads();
        s[t] += a;
        __syncthreads();
    }
    if (i < n) rp[i + 1] = s[t];
    if (t == TPB - 1) bsum[blockIdx.x] = s[t];
}

// exclusive scan of block sums (nb <= 256)
__global__ void k_scan_top(int* bsum, int nb) {
    __shared__ int s[TPB];
    int t = threadIdx.x;
    int v = (t < nb) ? bsum[t] : 0;
    s[t] = v;
    __syncthreads();
    for (int off = 1; off < TPB; off <<= 1) {
        int a = (t >= off) ? s[t - off] : 0;
        __syncthreads();
        s[t] += a;
        __syncthreads();
    }
    if (t < nb) bsum[t] = s[t] - v;  // exclusive
}

// rp finalize + dinv, fused
__global__ void k_scan_add_prep(int* rp, const int* __restrict__ bsum,
                                const int* __restrict__ cnt,
                                float* __restrict__ dinv, int n) {
    int i = blockIdx.x * TPB + threadIdx.x;
    if (i < n) {
        rp[i + 1] += bsum[i >> 8];
        dinv[i] = rsqrtf(1.0f + (float)cnt[i]);
    }
    if (i == 0) rp[0] = 0;
}

// non-atomic scatter: position precomputed by k_hist_pos
__global__ void k_fill_na(const int* __restrict__ src, const int* __restrict__ dst,
                          const int* __restrict__ rp, const int* __restrict__ epos,
                          int* __restrict__ csrc, int E) {
    int e = blockIdx.x * TPB + threadIdx.x;
    if (e < E) csrc[rp[dst[e]] + epos[e]] = src[e];
}

// ---------------- GEMM1: Hb = bf16( (x @ W1) * dinv[row] )  (128x128) ----------------
// K split into two 32 KiB LDS halves (5 blocks/CU) + 1-group-ahead x prefetch.

#define COMP(v, j) ((j) == 0 ? (v).x : ((j) == 1 ? (v).y : ((j) == 2 ? (v).z : (v).w)))

__global__ __launch_bounds__(256) void k_gemm1(const float* __restrict__ x,
                                               const float* __restrict__ W,
                                               const float* __restrict__ dinv,
                                               unsigned short* __restrict__ Hb, int n) {
    __shared__ float Wl[64 * 128];  // 32 KiB: half of W's K-rows
    int t = threadIdx.x;
    int cg = t & 31;                          // col group: cols cg*4 .. cg*4+3
    int r0 = blockIdx.x * 32 + (t >> 5) * 4;  // 4 rows per thread
    int ra = min(r0, n - 1), rb = min(r0 + 1, n - 1);
    int rc = min(r0 + 2, n - 1), rd = min(r0 + 3, n - 1);
    const float* x0 = x + (size_t)ra * 128;
    const float* x1 = x + (size_t)rb * 128;
    const float* x2 = x + (size_t)rc * 128;
    const float* x3 = x + (size_t)rd * 128;
    float4 a0 = make_float4(0, 0, 0, 0), a1 = a0, a2 = a0, a3 = a0;
    // current k-group x registers (k = 0..3)
    float4 ca = *(const float4*)(x0);
    float4 cb = *(const float4*)(x1);
    float4 cc = *(const float4*)(x2);
    float4 cd = *(const float4*)(x3);
    const float4* L4 = (const float4*)Wl;
    for (int p = 0; p < 2; ++p) {
        if (p) __syncthreads();  // prior pass reads done before overwrite
        {
            const float4* W4 = (const float4*)(W + (size_t)p * 64 * 128);
            float4* S4 = (float4*)Wl;
#pragma unroll
            for (int i = 0; i < 8; ++i) S4[t + i * 256] = W4[t + i * 256];
        }
        __syncthreads();
        for (int kg = 0; kg < 16; ++kg) {
            int kn = p * 64 + kg * 4 + 4;
            int knc = kn < 128 ? kn : 124;  // clamp: last prefetch is redundant, never used
            float4 na = *(const float4*)(x0 + knc);
            float4 nb = *(const float4*)(x1 + knc);
            float4 nc = *(const float4*)(x2 + knc);
            float4 nd = *(const float4*)(x3 + knc);
#pragma unroll
            for (int j = 0; j < 4; ++j) {
                float4 w = L4[(kg * 4 + j) * 32 + cg];
                float va = COMP(ca, j), vb = COMP(cb, j), vc = COMP(cc, j), vd = COMP(cd, j);
                a0.x = fmaf(va, w.x, a0.x); a0.y = fmaf(va, w.y, a0.y);
                a0.z = fmaf(va, w.z, a0.z); a0.w = fmaf(va, w.w, a0.w);
                a1.x = fmaf(vb, w.x, a1.x); a1.y = fmaf(vb, w.y, a1.y);
                a1.z = fmaf(vb, w.z, a1.z); a1.w = fmaf(vb, w.w, a1.w);
                a2.x = fmaf(vc, w.x, a2.x); a2.y = fmaf(vc, w.y, a2.y);
                a2.z = fmaf(vc, w.z, a2.z); a2.w = fmaf(vc, w.w, a2.w);
                a3.x = fmaf(vd, w.x, a3.x); a3.y = fmaf(vd, w.y, a3.y);
                a3.z = fmaf(vd, w.z, a3.z); a3.w = fmaf(vd, w.w, a3.w);
            }
            ca = na; cb = nb; cc = nc; cd = nd;
        }
    }
    if (r0 >= n) return;
    auto store = [&](int r, float4 a) {
        float s = dinv[r];
        ushort4 o;
        o.x = f2bf(a.x * s); o.y = f2bf(a.y * s); o.z = f2bf(a.z * s); o.w = f2bf(a.w * s);
        *(ushort4*)(Hb + (size_t)r * 128 + cg * 4) = o;
    };
    store(r0, a0);
    if (r0 + 1 < n) store(r0 + 1, a1);
    if (r0 + 2 < n) store(r0 + 2, a2);
    if (r0 + 3 < n) store(r0 + 3, a3);
}

// ---------------- agg1: h = relu( dinv[i] * (Hb[i] + sum_in Hb[s]) + b1 ) ----------------
// Hb rows are 128 bf16 = 64 uint32; lane handles features 2*lane, 2*lane+1.

__global__ __launch_bounds__(256) void k_agg1(const unsigned int* __restrict__ Hb32,
                                              const int* __restrict__ rp,
                                              const int* __restrict__ csrc,
                                              const float* __restrict__ dinv,
                                              const float* __restrict__ b1,
                                              float* __restrict__ hout, int n) {
    int i = blockIdx.x * 4 + (threadIdx.x >> 6);
    if (i >= n) return;
    int lane = threadIdx.x & 63;
    unsigned vself = Hb32[(size_t)i * 64 + lane];
    float s0x = __uint_as_float(vself << 16);
    float s0y = __uint_as_float(vself & 0xffff0000u);
    float s1x = 0.f, s1y = 0.f, s2x = 0.f, s2y = 0.f, s3x = 0.f, s3y = 0.f;
    int e = rp[i], end = rp[i + 1];
    for (; e + 8 <= end; e += 8) {
        int i0 = csrc[e], i1 = csrc[e + 1], i2 = csrc[e + 2], i3 = csrc[e + 3];
        int i4 = csrc[e + 4], i5 = csrc[e + 5], i6 = csrc[e + 6], i7 = csrc[e + 7];
        unsigned v0 = Hb32[(size_t)i0 * 64 + lane];
        unsigned v1 = Hb32[(size_t)i1 * 64 + lane];
        unsigned v2 = Hb32[(size_t)i2 * 64 + lane];
        unsigned v3 = Hb32[(size_t)i3 * 64 + lane];
        unsigned v4 = Hb32[(size_t)i4 * 64 + lane];
        unsigned v5 = Hb32[(size_t)i5 * 64 + lane];
        unsigned v6 = Hb32[(size_t)i6 * 64 + lane];
        unsigned v7 = Hb32[(size_t)i7 * 64 + lane];
        s0x += __uint_as_float(v0 << 16); s0y += __uint_as_float(v0 & 0xffff0000u);
        s1x += __uint_as_float(v1 << 16); s1y += __uint_as_float(v1 & 0xffff0000u);
        s2x += __uint_as_float(v2 << 16); s2y += __uint_as_float(v2 & 0xffff0000u);
        s3x += __uint_as_float(v3 << 16); s3y += __uint_as_float(v3 & 0xffff0000u);
        s0x += __uint_as_float(v4 << 16); s0y += __uint_as_float(v4 & 0xffff0000u);
        s1x += __uint_as_float(v5 << 16); s1y += __uint_as_float(v5 & 0xffff0000u);
        s2x += __uint_as_float(v6 << 16); s2y += __uint_as_float(v6 & 0xffff0000u);
        s3x += __uint_as_float(v7 << 16); s3y += __uint_as_float(v7 & 0xffff0000u);
    }
    for (; e + 2 <= end; e += 2) {
        int i0 = csrc[e], i1 = csrc[e + 1];
        unsigned v0 = Hb32[(size_t)i0 * 64 + lane];
        unsigned v1 = Hb32[(size_t)i1 * 64 + lane];
        s0x += __uint_as_float(v0 << 16); s0y += __uint_as_float(v0 & 0xffff0000u);
        s1x += __uint_as_float(v1 << 16); s1y += __uint_as_float(v1 & 0xffff0000u);
    }
    if (e < end) {
        unsigned v0 = Hb32[(size_t)csrc[e] * 64 + lane];
        s0x += __uint_as_float(v0 << 16); s0y += __uint_as_float(v0 & 0xffff0000u);
    }
    float di = dinv[i];
    float2 bb = ((const float2*)b1)[lane];
    float2 r;
    r.x = fmaxf(fmaf((s0x + s1x) + (s2x + s3x), di, bb.x), 0.f);
    r.y = fmaxf(fmaf((s0y + s1y) + (s2y + s3y), di, bb.y), 0.f);
    ((float2*)hout)[(size_t)i * 64 + lane] = r;
}

// ---------------- GEMM2: H2b = bf16( (h @ W2) * dinv[row] )  (128x40) ----------------

__global__ __launch_bounds__(256) void k_gemm2(const float* __restrict__ h,
                                               const float* __restrict__ W,
                                               const float* __restrict__ dinv,
                                               unsigned short* __restrict__ H2b, int n) {
    __shared__ float Wl[128 * 40];  // 20 KiB
    {
        const float4* W4 = (const float4*)W;
        float4* L4 = (float4*)Wl;
        for (int i = threadIdx.x; i < 128 * 10; i += TPB) L4[i] = W4[i];
    }
    __syncthreads();
    int t = threadIdx.x;
    if (t >= 250) return;
    int cg = t % 10;  // col group: cols cg*4 .. cg*4+3
    int rb = t / 10;
    int r0 = blockIdx.x * 100 + rb * 4;
    if (r0 >= n) return;
    int r1 = min(r0 + 1, n - 1), r2 = min(r0 + 2, n - 1), r3 = min(r0 + 3, n - 1);
    const float* h0 = h + (size_t)r0 * 128;
    const float* h1 = h + (size_t)r1 * 128;
    const float* h2 = h + (size_t)r2 * 128;
    const float* h3 = h + (size_t)r3 * 128;
    float4 a0 = make_float4(0, 0, 0, 0), a1 = a0, a2 = a0, a3 = a0;
    const float4* L4 = (const float4*)Wl;
    for (int k = 0; k < 128; k += 4) {
        float4 xa = *(const float4*)(h0 + k);
        float4 xb = *(const float4*)(h1 + k);
        float4 xc = *(const float4*)(h2 + k);
        float4 xd = *(const float4*)(h3 + k);
#pragma unroll
        for (int j = 0; j < 4; ++j) {
            float4 w = L4[(k + j) * 10 + cg];
            float va = COMP(xa, j), vb = COMP(xb, j), vc = COMP(xc, j), vd = COMP(xd, j);
            a0.x = fmaf(va, w.x, a0.x); a0.y = fmaf(va, w.y, a0.y);
            a0.z = fmaf(va, w.z, a0.z); a0.w = fmaf(va, w.w, a0.w);
            a1.x = fmaf(vb, w.x, a1.x); a1.y = fmaf(vb, w.y, a1.y);
            a1.z = fmaf(vb, w.z, a1.z); a1.w = fmaf(vb, w.w, a1.w);
            a2.x = fmaf(vc, w.x, a2.x); a2.y = fmaf(vc, w.y, a2.y);
            a2.z = fmaf(vc, w.z, a2.z); a2.w = fmaf(vc, w.w, a2.w);
            a3.x = fmaf(vd, w.x, a3.x); a3.y = fmaf(vd, w.y, a3.y);
            a3.z = fmaf(vd, w.z, a3.z); a3.w = fmaf(vd, w.w, a3.w);
        }
    }
    auto store = [&](int r, float4 a) {
        float s = dinv[r];
        ushort4 o;
        o.x = f2bf(a.x * s); o.y = f2bf(a.y * s); o.z = f2bf(a.z * s); o.w = f2bf(a.w * s);
        *(ushort4*)(H2b + (size_t)r * 40 + cg * 4) = o;
    };
    store(r0, a0);
    if (r0 + 1 < n) store(r0 + 1, a1);
    if (r0 + 2 < n) store(r0 + 2, a2);
    if (r0 + 3 < n) store(r0 + 3, a3);
}

// ---------------- agg2 + bias + log_softmax fused: one wave per node ----------------

__global__ __launch_bounds__(256) void k_agg2(const unsigned short* __restrict__ H2b,
                                              const int* __restrict__ rp,
                                              const int* __restrict__ csrc,
                                              const float* __restrict__ dinv,
                                              const float* __restrict__ b2,
                                              float* __restrict__ out, int n) {
    int i = blockIdx.x * 4 + (threadIdx.x >> 6);
    if (i >= n) return;
    int lane = threadIdx.x & 63;
    int c = lane < 40 ? lane : 39;  // clamp for loads; lanes >=40 masked at the end
    float s0 = bf2f(H2b[(size_t)i * 40 + c]);  // self message
    float s1 = 0.f, s2 = 0.f, s3 = 0.f;
    int e = rp[i], end = rp[i + 1];
    for (; e + 8 <= end; e += 8) {
        int i0 = csrc[e], i1 = csrc[e + 1], i2 = csrc[e + 2], i3 = csrc[e + 3];
        int i4 = csrc[e + 4], i5 = csrc[e + 5], i6 = csrc[e + 6], i7 = csrc[e + 7];
        float v0 = bf2f(H2b[(size_t)i0 * 40 + c]);
        float v1 = bf2f(H2b[(size_t)i1 * 40 + c]);
        float v2 = bf2f(H2b[(size_t)i2 * 40 + c]);
        float v3 = bf2f(H2b[(size_t)i3 * 40 + c]);
        float v4 = bf2f(H2b[(size_t)i4 * 40 + c]);
        float v5 = bf2f(H2b[(size_t)i5 * 40 + c]);
        float v6 = bf2f(H2b[(size_t)i6 * 40 + c]);
        float v7 = bf2f(H2b[(size_t)i7 * 40 + c]);
        s0 += v0; s1 += v1; s2 += v2; s3 += v3;
        s0 += v4; s1 += v5; s2 += v6; s3 += v7;
    }
    for (; e + 2 <= end; e += 2) {
        s0 += bf2f(H2b[(size_t)csrc[e] * 40 + c]);
        s1 += bf2f(H2b[(size_t)csrc[e + 1] * 40 + c]);
    }
    if (e < end) s0 += bf2f(H2b[(size_t)csrc[e] * 40 + c]);
    float di = dinv[i];
    float val = fmaf((s0 + s1) + (s2 + s3), di, b2[c]);
    float m = (lane < 40) ? val : -INFINITY;
#pragma unroll
    for (int off = 32; off; off >>= 1) m = fmaxf(m, __shfl_xor(m, off));
    float ex = (lane < 40) ? expf(val - m) : 0.f;
    float s = ex;
#pragma unroll
    for (int off = 32; off; off >>= 1) s += __shfl_xor(s, off);
    float ls = logf(s);
    if (lane < 40) out[(size_t)i * 40 + lane] = val - m - ls;
}

// ---------------- launch ----------------

extern "C" void kernel_launch(void* const* d_in, const int* in_sizes, int n_in,
                              void* d_out, int out_size, void* d_ws, size_t ws_size,
                              hipStream_t stream) {
    const float* x  = (const float*)d_in[0];
    const int*   ei = (const int*)d_in[1];
    const float* W1 = (const float*)d_in[2];
    const float* b1 = (const float*)d_in[3];
    const float* W2 = (const float*)d_in[4];
    const float* b2 = (const float*)d_in[5];

    int n = in_sizes[0] / 128;
    int E = in_sizes[1] / 2;
    const int* src = ei;
    const int* dst = ei + E;

    float* out = (float*)d_out;

    // workspace layout (4-byte units, 16B-aligned chunks)
    char* wsb = (char*)d_ws;
    size_t off = 0;
    auto alloc = [&](size_t elems4) {
        size_t o = off;
        off += ((elems4 + 3) & ~(size_t)3) * 4;
        return o;
    };
    float* dinv = (float*)(wsb + alloc(n));
    int* cnt    = (int*)(wsb + alloc(n));
    int* rp     = (int*)(wsb + alloc(n + 1));
    int* bsum   = (int*)(wsb + alloc(256));
    int* epos   = (int*)(wsb + alloc(E));
    int* csrc   = (int*)(wsb + alloc(E));
    unsigned int* Hb32   = (unsigned int*)(wsb + alloc((size_t)n * 64));   // H1' bf16, 12.8 MB
    float* hout          = (float*)(wsb + alloc((size_t)n * 128));         // relu(h1), 25.6 MB
    unsigned short* H2b  = (unsigned short*)(wsb + alloc((size_t)n * 20)); // H2' bf16, 4 MB

    int nbN = (n + TPB - 1) / TPB;   // must be <= 256 for scan_top (50000/256=196, ok)
    int nbE = (E + TPB - 1) / TPB;

    k_zero<<<nbN, TPB, 0, stream>>>(cnt, n);
    k_hist_pos<<<nbE, TPB, 0, stream>>>(dst, cnt, epos, E);
    k_scan_block<<<nbN, TPB, 0, stream>>>(cnt, rp, bsum, n);
    k_scan_top<<<1, TPB, 0, stream>>>(bsum, nbN);
    k_scan_add_prep<<<nbN, TPB, 0, stream>>>(rp, bsum, cnt, dinv, n);
    k_fill_na<<<nbE, TPB, 0, stream>>>(src, dst, rp, epos, csrc, E);

    k_gemm1<<<(n + 31) / 32, TPB, 0, stream>>>(x, W1, dinv, (unsigned short*)Hb32, n);
    k_agg1<<<(n + 3) / 4, TPB, 0, stream>>>(Hb32, rp, csrc, dinv, b1, hout, n);
    k_gemm2<<<(n + 99) / 100, TPB, 0, stream>>>(hout, W2, dinv, H2b, n);
    k_agg2<<<(n + 3) / 4, TPB, 0, stream>>>(H2b, rp, csrc, dinv, b2, out, n);
}

// Round 9
// 166.231 us; speedup vs baseline: 4.7874x; 1.1419x over previous
//
#include <hip/hip_runtime.h>
#include <math.h>

static constexpr int TPB = 256;

typedef short bf16x8 __attribute__((ext_vector_type(8)));
typedef float f32x4 __attribute__((ext_vector_type(4)));

// float -> bf16 (round-to-nearest-even), finite inputs
__device__ inline unsigned short f2bf(float f) {
    unsigned u = __float_as_uint(f);
    return (unsigned short)((u + 0x7fffu + ((u >> 16) & 1u)) >> 16);
}
__device__ inline float bf2f(unsigned short b) {
    return __uint_as_float(((unsigned)b) << 16);
}

// ---------------- CSR build ----------------

__global__ void k_zero(int* p, int n) {
    int i = blockIdx.x * TPB + threadIdx.x;
    if (i < n) p[i] = 0;
}

// histogram + per-edge position; counters padded to one per 64B line to kill
// per-line atomic serialization (memory-side RMW is 64B granular)
__global__ void k_hist_pos(const int* __restrict__ dst, int* __restrict__ cntp,
                           int* __restrict__ epos, int E) {
    int e = blockIdx.x * TPB + threadIdx.x;
    if (e < E) epos[e] = atomicAdd(&cntp[(size_t)dst[e] << 4], 1);
}

// per-block inclusive scan of cntp (strided) -> rp[i+1]; block totals -> bsum
__global__ void k_scan_block(const int* __restrict__ cntp, int* __restrict__ rp,
                             int* __restrict__ bsum, int n) {
    __shared__ int s[TPB];
    int t = threadIdx.x;
    int i = blockIdx.x * TPB + t;
    int v = (i < n) ? cntp[(size_t)i << 4] : 0;
    s[t] = v;
    __syncthreads();
    for (int off = 1; off < TPB; off <<= 1) {
        int a = (t >= off) ? s[t - off] : 0;
        __syncthreads();
        s[t] += a;
        __syncthreads();
    }
    if (i < n) rp[i + 1] = s[t];
    if (t == TPB - 1) bsum[blockIdx.x] = s[t];
}

// exclusive scan of block sums (nb <= 256)
__global__ void k_scan_top(int* bsum, int nb) {
    __shared__ int s[TPB];
    int t = threadIdx.x;
    int v = (t < nb) ? bsum[t] : 0;
    s[t] = v;
    __syncthreads();
    for (int off = 1; off < TPB; off <<= 1) {
        int a = (t >= off) ? s[t - off] : 0;
        __syncthreads();
        s[t] += a;
        __syncthreads();
    }
    if (t < nb) bsum[t] = s[t] - v;  // exclusive
}

// rp finalize + dinv, fused
__global__ void k_scan_add_prep(int* rp, const int* __restrict__ bsum,
                                const int* __restrict__ cntp,
                                float* __restrict__ dinv, int n) {
    int i = blockIdx.x * TPB + threadIdx.x;
    if (i < n) {
        rp[i + 1] += bsum[i >> 8];
        dinv[i] = rsqrtf(1.0f + (float)cntp[(size_t)i << 4]);
    }
    if (i == 0) rp[0] = 0;
}

// non-atomic scatter: position precomputed by k_hist_pos
__global__ void k_fill_na(const int* __restrict__ src, const int* __restrict__ dst,
                          const int* __restrict__ rp, const int* __restrict__ epos,
                          int* __restrict__ csrc, int E) {
    int e = blockIdx.x * TPB + threadIdx.x;
    if (e < E) csrc[rp[dst[e]] + epos[e]] = src[e];
}

// ---------------- GEMM1 (MFMA): Hb = bf16( (x @ W1) * dinv[row] ) ----------------
// 64-row blocks, 4 waves; wave w computes rows w*16..+15 x all 128 cols.
// LDS: x tile [64][128] bf16 (16KB) + W^T [n=128][k=128] bf16 (32KB), both
// XOR-swizzled (byte ^= (row&7)<<4) on write AND read (T2; rule 21).
// Fragment layouts (mfma_f32_16x16x32_bf16, m89-verified D):
//   A: m=lane&15, k=(lane>>4)*8+j   B: n=lane&15, k=(lane>>4)*8+j
//   D: n=lane&15, m=(lane>>4)*4+reg

__global__ __launch_bounds__(256) void k_gemm1_mfma(const float* __restrict__ x,
                                                    const float* __restrict__ W,
                                                    const float* __restrict__ dinv,
                                                    unsigned short* __restrict__ Hb,
                                                    int n) {
    __shared__ unsigned short xt[64 * 128];    // 16 KB
    __shared__ unsigned short wt[128 * 128];   // 32 KB, transposed: wt[n][k]
    int t = threadIdx.x;
    int row0 = blockIdx.x * 64;

    // stage W^T: thread t handles n = t&127, k-half = (t>>7)*64, 8 groups of 8 k
    {
        int nn = t & 127;
        int kh = (t >> 7) * 64;
        unsigned swz = (unsigned)((nn & 7) << 4);
#pragma unroll
        for (int g = 0; g < 8; ++g) {
            int k0 = kh + g * 8;
            bf16x8 bv;
#pragma unroll
            for (int j = 0; j < 8; ++j)
                bv[j] = (short)f2bf(W[(size_t)(k0 + j) * 128 + nn]);  // coalesced over nn
            unsigned byteoff = ((unsigned)(nn * 256 + k0 * 2)) ^ swz; // 16B-aligned
            *(bf16x8*)((char*)wt + byteoff) = bv;
        }
    }
    // stage x tile: 2048 float4s, thread t handles flat = t + i*256
    {
#pragma unroll
        for (int i = 0; i < 8; ++i) {
            int flat = t + i * 256;
            int r = flat >> 5;   // 0..63
            int k4 = flat & 31;  // float4 index within row
            int gr = row0 + r;
            if (gr > n - 1) gr = n - 1;
            float4 v = *(const float4*)(x + (size_t)gr * 128 + k4 * 4);
            unsigned o0 = (unsigned)f2bf(v.x) | ((unsigned)f2bf(v.y) << 16);
            unsigned o1 = (unsigned)f2bf(v.z) | ((unsigned)f2bf(v.w) << 16);
            uint2 u = make_uint2(o0, o1);
            unsigned byteoff = ((unsigned)(r * 256 + k4 * 8)) ^ ((unsigned)((r & 7) << 4));
            *(uint2*)((char*)xt + byteoff) = u;  // 8B write, swizzle is 16B-granular: ok
        }
    }
    __syncthreads();

    int wv = t >> 6;        // wave 0..3
    int l = t & 63;
    int lm = l & 15;        // A-row / B-col / D-col within tile
    int lk = (l >> 4) * 8;  // k base (8 contiguous)

    // A fragments for this wave's 16 rows, all 4 k-steps
    bf16x8 af[4];
#pragma unroll
    for (int ks = 0; ks < 4; ++ks) {
        int r = wv * 16 + lm;
        unsigned byteoff =
            ((unsigned)(r * 256 + (ks * 32 + lk) * 2)) ^ ((unsigned)((r & 7) << 4));
        af[ks] = *(bf16x8*)((char*)xt + byteoff);
    }

    for (int ct = 0; ct < 8; ++ct) {
        f32x4 acc = {0.f, 0.f, 0.f, 0.f};
#pragma unroll
        for (int ks = 0; ks < 4; ++ks) {
            int nn = ct * 16 + lm;
            unsigned byteoff =
                ((unsigned)(nn * 256 + (ks * 32 + lk) * 2)) ^ ((unsigned)((nn & 7) << 4));
            bf16x8 bfr = *(bf16x8*)((char*)wt + byteoff);
            acc = __builtin_amdgcn_mfma_f32_16x16x32_bf16(af[ks], bfr, acc, 0, 0, 0);
        }
        int mb = (l >> 4) * 4;
#pragma unroll
        for (int r = 0; r < 4; ++r) {
            int grow = row0 + wv * 16 + mb + r;
            if (grow < n) {
                float s = dinv[grow];
                Hb[(size_t)grow * 128 + ct * 16 + lm] = f2bf(acc[r] * s);
            }
        }
    }
}

// ---------------- agg1: h = relu( dinv[i] * (Hb[i] + sum_in Hb[s]) + b1 ) ----------------
// Hb rows are 128 bf16 = 64 uint32; lane handles features 2*lane, 2*lane+1.

__global__ __launch_bounds__(256) void k_agg1(const unsigned int* __restrict__ Hb32,
                                              const int* __restrict__ rp,
                                              const int* __restrict__ csrc,
                                              const float* __restrict__ dinv,
                                              const float* __restrict__ b1,
                                              float* __restrict__ hout, int n) {
    int i = blockIdx.x * 4 + (threadIdx.x >> 6);
    if (i >= n) return;
    int lane = threadIdx.x & 63;
    unsigned vself = Hb32[(size_t)i * 64 + lane];
    float s0x = __uint_as_float(vself << 16);
    float s0y = __uint_as_float(vself & 0xffff0000u);
    float s1x = 0.f, s1y = 0.f, s2x = 0.f, s2y = 0.f, s3x = 0.f, s3y = 0.f;
    int e = rp[i], end = rp[i + 1];
    for (; e + 8 <= end; e += 8) {
        int i0 = csrc[e], i1 = csrc[e + 1], i2 = csrc[e + 2], i3 = csrc[e + 3];
        int i4 = csrc[e + 4], i5 = csrc[e + 5], i6 = csrc[e + 6], i7 = csrc[e + 7];
        unsigned v0 = Hb32[(size_t)i0 * 64 + lane];
        unsigned v1 = Hb32[(size_t)i1 * 64 + lane];
        unsigned v2 = Hb32[(size_t)i2 * 64 + lane];
        unsigned v3 = Hb32[(size_t)i3 * 64 + lane];
        unsigned v4 = Hb32[(size_t)i4 * 64 + lane];
        unsigned v5 = Hb32[(size_t)i5 * 64 + lane];
        unsigned v6 = Hb32[(size_t)i6 * 64 + lane];
        unsigned v7 = Hb32[(size_t)i7 * 64 + lane];
        s0x += __uint_as_float(v0 << 16); s0y += __uint_as_float(v0 & 0xffff0000u);
        s1x += __uint_as_float(v1 << 16); s1y += __uint_as_float(v1 & 0xffff0000u);
        s2x += __uint_as_float(v2 << 16); s2y += __uint_as_float(v2 & 0xffff0000u);
        s3x += __uint_as_float(v3 << 16); s3y += __uint_as_float(v3 & 0xffff0000u);
        s0x += __uint_as_float(v4 << 16); s0y += __uint_as_float(v4 & 0xffff0000u);
        s1x += __uint_as_float(v5 << 16); s1y += __uint_as_float(v5 & 0xffff0000u);
        s2x += __uint_as_float(v6 << 16); s2y += __uint_as_float(v6 & 0xffff0000u);
        s3x += __uint_as_float(v7 << 16); s3y += __uint_as_float(v7 & 0xffff0000u);
    }
    for (; e + 2 <= end; e += 2) {
        int i0 = csrc[e], i1 = csrc[e + 1];
        unsigned v0 = Hb32[(size_t)i0 * 64 + lane];
        unsigned v1 = Hb32[(size_t)i1 * 64 + lane];
        s0x += __uint_as_float(v0 << 16); s0y += __uint_as_float(v0 & 0xffff0000u);
        s1x += __uint_as_float(v1 << 16); s1y += __uint_as_float(v1 & 0xffff0000u);
    }
    if (e < end) {
        unsigned v0 = Hb32[(size_t)csrc[e] * 64 + lane];
        s0x += __uint_as_float(v0 << 16); s0y += __uint_as_float(v0 & 0xffff0000u);
    }
    float di = dinv[i];
    float2 bb = ((const float2*)b1)[lane];
    float2 r;
    r.x = fmaxf(fmaf((s0x + s1x) + (s2x + s3x), di, bb.x), 0.f);
    r.y = fmaxf(fmaf((s0y + s1y) + (s2y + s3y), di, bb.y), 0.f);
    ((float2*)hout)[(size_t)i * 64 + lane] = r;
}

// ---------------- GEMM2: H2b = bf16( (h @ W2) * dinv[row] )  (128x40) ----------------

#define COMP(v, j) ((j) == 0 ? (v).x : ((j) == 1 ? (v).y : ((j) == 2 ? (v).z : (v).w)))

__global__ __launch_bounds__(256) void k_gemm2(const float* __restrict__ h,
                                               const float* __restrict__ W,
                                               const float* __restrict__ dinv,
                                               unsigned short* __restrict__ H2b, int n) {
    __shared__ float Wl[128 * 40];  // 20 KiB
    {
        const float4* W4 = (const float4*)W;
        float4* L4 = (float4*)Wl;
        for (int i = threadIdx.x; i < 128 * 10; i += TPB) L4[i] = W4[i];
    }
    __syncthreads();
    int t = threadIdx.x;
    if (t >= 250) return;
    int cg = t % 10;  // col group: cols cg*4 .. cg*4+3
    int rb = t / 10;
    int r0 = blockIdx.x * 100 + rb * 4;
    if (r0 >= n) return;
    int r1 = min(r0 + 1, n - 1), r2 = min(r0 + 2, n - 1), r3 = min(r0 + 3, n - 1);
    const float* h0 = h + (size_t)r0 * 128;
    const float* h1 = h + (size_t)r1 * 128;
    const float* h2 = h + (size_t)r2 * 128;
    const float* h3 = h + (size_t)r3 * 128;
    float4 a0 = make_float4(0, 0, 0, 0), a1 = a0, a2 = a0, a3 = a0;
    const float4* L4 = (const float4*)Wl;
    for (int k = 0; k < 128; k += 4) {
        float4 xa = *(const float4*)(h0 + k);
        float4 xb = *(const float4*)(h1 + k);
        float4 xc = *(const float4*)(h2 + k);
        float4 xd = *(const float4*)(h3 + k);
#pragma unroll
        for (int j = 0; j < 4; ++j) {
            float4 w = L4[(k + j) * 10 + cg];
            float va = COMP(xa, j), vb = COMP(xb, j), vc = COMP(xc, j), vd = COMP(xd, j);
            a0.x = fmaf(va, w.x, a0.x); a0.y = fmaf(va, w.y, a0.y);
            a0.z = fmaf(va, w.z, a0.z); a0.w = fmaf(va, w.w, a0.w);
            a1.x = fmaf(vb, w.x, a1.x); a1.y = fmaf(vb, w.y, a1.y);
            a1.z = fmaf(vb, w.z, a1.z); a1.w = fmaf(vb, w.w, a1.w);
            a2.x = fmaf(vc, w.x, a2.x); a2.y = fmaf(vc, w.y, a2.y);
            a2.z = fmaf(vc, w.z, a2.z); a2.w = fmaf(vc, w.w, a2.w);
            a3.x = fmaf(vd, w.x, a3.x); a3.y = fmaf(vd, w.y, a3.y);
            a3.z = fmaf(vd, w.z, a3.z); a3.w = fmaf(vd, w.w, a3.w);
        }
    }
    auto store = [&](int r, float4 a) {
        float s = dinv[r];
        ushort4 o;
        o.x = f2bf(a.x * s); o.y = f2bf(a.y * s); o.z = f2bf(a.z * s); o.w = f2bf(a.w * s);
        *(ushort4*)(H2b + (size_t)r * 40 + cg * 4) = o;
    };
    store(r0, a0);
    if (r0 + 1 < n) store(r0 + 1, a1);
    if (r0 + 2 < n) store(r0 + 2, a2);
    if (r0 + 3 < n) store(r0 + 3, a3);
}

// ---------------- agg2 + bias + log_softmax fused: one wave per node ----------------

__global__ __launch_bounds__(256) void k_agg2(const unsigned short* __restrict__ H2b,
                                              const int* __restrict__ rp,
                                              const int* __restrict__ csrc,
                                              const float* __restrict__ dinv,
                                              const float* __restrict__ b2,
                                              float* __restrict__ out, int n) {
    int i = blockIdx.x * 4 + (threadIdx.x >> 6);
    if (i >= n) return;
    int lane = threadIdx.x & 63;
    int c = lane < 40 ? lane : 39;  // clamp for loads; lanes >=40 masked at the end
    float s0 = bf2f(H2b[(size_t)i * 40 + c]);  // self message
    float s1 = 0.f, s2 = 0.f, s3 = 0.f;
    int e = rp[i], end = rp[i + 1];
    for (; e + 8 <= end; e += 8) {
        int i0 = csrc[e], i1 = csrc[e + 1], i2 = csrc[e + 2], i3 = csrc[e + 3];
        int i4 = csrc[e + 4], i5 = csrc[e + 5], i6 = csrc[e + 6], i7 = csrc[e + 7];
        float v0 = bf2f(H2b[(size_t)i0 * 40 + c]);
        float v1 = bf2f(H2b[(size_t)i1 * 40 + c]);
        float v2 = bf2f(H2b[(size_t)i2 * 40 + c]);
        float v3 = bf2f(H2b[(size_t)i3 * 40 + c]);
        float v4 = bf2f(H2b[(size_t)i4 * 40 + c]);
        float v5 = bf2f(H2b[(size_t)i5 * 40 + c]);
        float v6 = bf2f(H2b[(size_t)i6 * 40 + c]);
        float v7 = bf2f(H2b[(size_t)i7 * 40 + c]);
        s0 += v0; s1 += v1; s2 += v2; s3 += v3;
        s0 += v4; s1 += v5; s2 += v6; s3 += v7;
    }
    for (; e + 2 <= end; e += 2) {
        s0 += bf2f(H2b[(size_t)csrc[e] * 40 + c]);
        s1 += bf2f(H2b[(size_t)csrc[e + 1] * 40 + c]);
    }
    if (e < end) s0 += bf2f(H2b[(size_t)csrc[e] * 40 + c]);
    float di = dinv[i];
    float val = fmaf((s0 + s1) + (s2 + s3), di, b2[c]);
    float m = (lane < 40) ? val : -INFINITY;
#pragma unroll
    for (int off = 32; off; off >>= 1) m = fmaxf(m, __shfl_xor(m, off));
    float ex = (lane < 40) ? expf(val - m) : 0.f;
    float s = ex;
#pragma unroll
    for (int off = 32; off; off >>= 1) s += __shfl_xor(s, off);
    float ls = logf(s);
    if (lane < 40) out[(size_t)i * 40 + lane] = val - m - ls;
}

// ---------------- launch ----------------

extern "C" void kernel_launch(void* const* d_in, const int* in_sizes, int n_in,
                              void* d_out, int out_size, void* d_ws, size_t ws_size,
                              hipStream_t stream) {
    const float* x  = (const float*)d_in[0];
    const int*   ei = (const int*)d_in[1];
    const float* W1 = (const float*)d_in[2];
    const float* b1 = (const float*)d_in[3];
    const float* W2 = (const float*)d_in[4];
    const float* b2 = (const float*)d_in[5];

    int n = in_sizes[0] / 128;
    int E = in_sizes[1] / 2;
    const int* src = ei;
    const int* dst = ei + E;

    float* out = (float*)d_out;

    // workspace layout (4-byte units, 16B-aligned chunks)
    char* wsb = (char*)d_ws;
    size_t off = 0;
    auto alloc = [&](size_t elems4) {
        size_t o = off;
        off += ((elems4 + 3) & ~(size_t)3) * 4;
        return o;
    };
    float* dinv = (float*)(wsb + alloc(n));
    int* cntp   = (int*)(wsb + alloc((size_t)n * 16));  // 64B-padded counters, 3.2 MB
    int* rp     = (int*)(wsb + alloc(n + 1));
    int* bsum   = (int*)(wsb + alloc(256));
    int* epos   = (int*)(wsb + alloc(E));
    int* csrc   = (int*)(wsb + alloc(E));
    unsigned int* Hb32   = (unsigned int*)(wsb + alloc((size_t)n * 64));   // H1' bf16
    float* hout          = (float*)(wsb + alloc((size_t)n * 128));         // relu(h1)
    unsigned short* H2b  = (unsigned short*)(wsb + alloc((size_t)n * 20)); // H2' bf16

    int nbN = (n + TPB - 1) / TPB;   // must be <= 256 for scan_top (50000/256=196, ok)
    int nbE = (E + TPB - 1) / TPB;

    k_zero<<<(int)(((size_t)n * 16 + TPB - 1) / TPB), TPB, 0, stream>>>(cntp, n * 16);
    k_hist_pos<<<nbE, TPB, 0, stream>>>(dst, cntp, epos, E);
    k_scan_block<<<nbN, TPB, 0, stream>>>(cntp, rp, bsum, n);
    k_scan_top<<<1, TPB, 0, stream>>>(bsum, nbN);
    k_scan_add_prep<<<nbN, TPB, 0, stream>>>(rp, bsum, cntp, dinv, n);
    k_fill_na<<<nbE, TPB, 0, stream>>>(src, dst, rp, epos, csrc, E);

    k_gemm1_mfma<<<(n + 63) / 64, TPB, 0, stream>>>(x, W1, dinv, (unsigned short*)Hb32, n);
    k_agg1<<<(n + 3) / 4, TPB, 0, stream>>>(Hb32, rp, csrc, dinv, b1, hout, n);
    k_gemm2<<<(n + 99) / 100, TPB, 0, stream>>>(hout, W2, dinv, H2b, n);
    k_agg2<<<(n + 3) / 4, TPB, 0, stream>>>(H2b, rp, csrc, dinv, b2, out, n);
}